// Round 7
// baseline (454.206 us; speedup 1.0000x reference)
//
#include <hip/hip_runtime.h>

typedef unsigned short u16;
typedef __attribute__((ext_vector_type(8))) short short8_t;
typedef __attribute__((ext_vector_type(4))) float floatx4;

typedef const void __attribute__((address_space(1)))* gas_ptr;
typedef void __attribute__((address_space(3)))* las_ptr;

__device__ __forceinline__ float bf2f(u16 u){
  union { unsigned i; float f; } v; v.i = ((unsigned)u) << 16; return v.f;
}
__device__ __forceinline__ u16 f2bf(float x){
  unsigned u = __float_as_uint(x);
  return (u16)((u + 0x7FFFu + ((u >> 16) & 1u)) >> 16);
}
__device__ __forceinline__ int bucket_idx(int delta){
  int b;
  if (delta >= -128 && delta <= 128) b = delta;
  else {
    float a = (float)(delta < 0 ? -delta : delta);
    float lp = ceilf(logf(a * (1.0f / 128.0f)) / logf(511.0f / 128.0f) * 127.0f) + 128.0f;
    b = (int)lp;
    if (delta < 0) b = -b;
  }
  int idx = b + 256;
  return idx < 0 ? 0 : (idx > 511 ? 511 : idx);
}

// ---------------- fused prep kernel ----------------
// blocks [0,4096): hs f32->bf16   [4096,5632): 6 weight transposes (z<5 -> Wt5, z=5 -> Wo_t)
// [5632,6144): rel_emb LayerNorm  6144: tables + bias concat
__global__ __launch_bounds__(256) void k_prep(
    const float* __restrict__ hs,
    const float* __restrict__ W0, const float* __restrict__ W1, const float* __restrict__ W2,
    const float* __restrict__ W3, const float* __restrict__ W4, const float* __restrict__ W5,
    const float* __restrict__ rel, const float* __restrict__ lng, const float* __restrict__ lnb,
    const float* __restrict__ bq, const float* __restrict__ bk, const float* __restrict__ bv,
    const float* __restrict__ bpk, const float* __restrict__ bpq,
    u16* __restrict__ h_bf, u16* __restrict__ Wt5, u16* __restrict__ Wo_t,
    u16* __restrict__ re_bf, u16* __restrict__ idxt, u16* __restrict__ ixlo_tbl,
    float* __restrict__ qkvb, float* __restrict__ posb)
{
  __shared__ float t[64][65];
  const int bid = blockIdx.x, tid = threadIdx.x;
  if (bid < 4096){
    int i = bid * 256 + tid;
    float4 v = ((const float4*)hs)[i];
    ushort4 o;
    o.x = f2bf(v.x); o.y = f2bf(v.y); o.z = f2bf(v.z); o.w = f2bf(v.w);
    ((ushort4*)h_bf)[i] = o;
  } else if (bid < 5632){
    int b2 = bid - 4096;
    int z = b2 >> 8, rem = b2 & 255;
    const float* W = (z == 0) ? W0 : (z == 1) ? W1 : (z == 2) ? W2 : (z == 3) ? W3 : (z == 4) ? W4 : W5;
    u16* Wt = (z < 5) ? (Wt5 + (long)z * 1048576) : Wo_t;
    int n0 = (rem & 15) * 64, k0 = (rem >> 4) * 64;
    #pragma unroll
    for (int i = 0; i < 16; i++){
      int e = i * 256 + tid; int r = e >> 6, c = e & 63;
      t[r][c] = W[(long)(k0 + r) * 1024 + n0 + c];
    }
    __syncthreads();
    #pragma unroll
    for (int i = 0; i < 16; i++){
      int e = i * 256 + tid; int r = e >> 6, c = e & 63;
      Wt[(long)(n0 + r) * 1024 + k0 + c] = f2bf(t[c][r]);
    }
  } else if (bid < 6144){
    int row = bid - 5632;
    float* red = (float*)t;
    float4 v = ((const float4*)(rel + (long)row * 1024))[tid];
    float s  = v.x + v.y + v.z + v.w;
    float s2 = v.x*v.x + v.y*v.y + v.z*v.z + v.w*v.w;
    #pragma unroll
    for (int o = 1; o < 64; o <<= 1){ s += __shfl_xor(s, o); s2 += __shfl_xor(s2, o); }
    if ((tid & 63) == 0){ red[(tid >> 6) * 2] = s; red[(tid >> 6) * 2 + 1] = s2; }
    __syncthreads();
    s  = red[0] + red[2] + red[4] + red[6];
    s2 = red[1] + red[3] + red[5] + red[7];
    float mu  = s * (1.f / 1024.f);
    float var = s2 * (1.f / 1024.f) - mu * mu;
    float rs  = rsqrtf(var + 1e-5f);
    float4 gg = ((const float4*)lng)[tid];
    float4 bb = ((const float4*)lnb)[tid];
    ushort4 o;
    o.x = f2bf((v.x - mu) * rs * gg.x + bb.x);
    o.y = f2bf((v.y - mu) * rs * gg.y + bb.y);
    o.z = f2bf((v.z - mu) * rs * gg.z + bb.z);
    o.w = f2bf((v.w - mu) * rs * gg.w + bb.w);
    ((ushort4*)(re_bf + (long)row * 1024))[tid] = o;
  } else {
    for (int i = tid; i < 2048; i += 256)
      idxt[i] = (u16)bucket_idx(i - 1024);
    if (tid < 256){
      int sb = tid >> 4, tt = tid & 15;
      int dlo = sb * 64 - tt * 64 - 63;
      int lo = bucket_idx(dlo) & ~1;
      if (lo > 384) lo = 384;
      ixlo_tbl[tid] = (u16)lo;
    }
    for (int i = tid; i < 1024; i += 256){
      qkvb[i] = bq[i]; qkvb[1024 + i] = bk[i]; qkvb[2048 + i] = bv[i];
      posb[i] = bpk[i]; posb[1024 + i] = bpq[i];
    }
  }
}

// ---------------- MFMA GEMM ----------------
// MODE 0: f32 rowmajor   MODE 3: pos GEMM z in {0,1}
// MODE 4: c2p/p2c batched z in [0,128)   MODE 5: fused QKV N=3072
template<int MODE>
__global__ __launch_bounds__(256) void k_gemm(
    const u16* __restrict__ A, const u16* __restrict__ Bt,
    const float* __restrict__ bias, void* __restrict__ C, void* __restrict__ C2,
    int M, int N, int K, int lda, int ldb)
{
  __shared__ __attribute__((aligned(16))) u16 smem[16384];
  u16* As = smem;
  u16* Bs = smem + 8192;
  const int z = blockIdx.z;
  const u16* Ab = A;
  const u16* Bb = Bt;
  if (MODE == 3){ Bb = Bt + (long)z * 1048576; bias += z << 10; }
  if (MODE == 4){ Ab = A + (long)z * 65536; Bb = Bt + (long)(z >> 6) * 524288 + (long)(z & 15) * 32768; }
  const int m0 = blockIdx.y * 128, n0 = blockIdx.x * 128;
  const int tid = threadIdx.x, lane = tid & 63, w = tid >> 6;
  const int wm = (w >> 1) * 64, wn = (w & 1) * 64;
  floatx4 acc[4][4];
  #pragma unroll
  for (int i = 0; i < 4; i++)
    #pragma unroll
    for (int j = 0; j < 4; j++) acc[i][j] = (floatx4){0.f, 0.f, 0.f, 0.f};

  const int r8 = lane >> 3;
  const int cswz = ((lane & 7) ^ r8) << 4;

  for (int kt = 0; kt < K; kt += 64){
    #pragma unroll
    for (int c = 0; c < 4; c++){
      int row = (c * 4 + w) * 8 + r8;
      const char* ga = (const char*)(Ab + (long)(m0 + row) * lda + kt) + cswz;
      __builtin_amdgcn_global_load_lds((gas_ptr)ga, (las_ptr)((char*)As + (c * 4 + w) * 1024), 16, 0, 0);
      const char* gb = (const char*)(Bb + (long)(n0 + row) * ldb + kt) + cswz;
      __builtin_amdgcn_global_load_lds((gas_ptr)gb, (las_ptr)((char*)Bs + (c * 4 + w) * 1024), 16, 0, 0);
    }
    __syncthreads();
    short8_t af[2][4], bfr[2][4];
    #pragma unroll
    for (int kk = 0; kk < 2; kk++){
      #pragma unroll
      for (int i = 0; i < 4; i++){
        int ra = wm + i * 16 + (lane & 15);
        af[kk][i] = *(const short8_t*)((const char*)As + ra * 128 + ((kk * 64 + ((lane >> 4) << 4)) ^ ((ra & 7) << 4)));
        int rb = wn + i * 16 + (lane & 15);
        bfr[kk][i] = *(const short8_t*)((const char*)Bs + rb * 128 + ((kk * 64 + ((lane >> 4) << 4)) ^ ((rb & 7) << 4)));
      }
    }
    #pragma unroll
    for (int i = 0; i < 4; i++)
      #pragma unroll
      for (int j = 0; j < 4; j++){
        acc[i][j] = __builtin_amdgcn_mfma_f32_16x16x32_bf16(af[0][i], bfr[0][j], acc[i][j], 0, 0, 0);
        acc[i][j] = __builtin_amdgcn_mfma_f32_16x16x32_bf16(af[1][i], bfr[1][j], acc[i][j], 0, 0, 0);
      }
    __syncthreads();
  }

  if (MODE == 5 && n0 >= 2048){
    #pragma unroll
    for (int i = 0; i < 4; i++){
      #pragma unroll
      for (int j = 0; j < 4; j++){
        #pragma unroll
        for (int r = 0; r < 4; r++){
          int ml = wm + i * 16 + ((lane >> 4) << 2) + r;
          int nl = wn + j * 16 + (lane & 15);
          float v = acc[i][j][r] + bias[n0 + nl];
          int byte_ = nl * 256 + ((ml * 2) ^ ((nl & 7) << 4));
          *(u16*)((char*)smem + byte_) = f2bf(v);
        }
      }
    }
    __syncthreads();
    #pragma unroll
    for (int rr = 0; rr < 8; rr++){
      int nl = rr * 16 + (tid >> 4);
      int np = n0 + nl - 2048;
      int mc = tid & 15;
      short8_t vv = *(const short8_t*)((const char*)smem + nl * 256 + ((mc * 16) ^ ((nl & 7) << 4)));
      int m = m0 + mc * 8;
      long base = ((long)((m >> 10) * 16 + (np >> 6)) * 64 + (np & 63)) * 1024 + (m & 1023);
      *(short8_t*)((u16*)C2 + base) = vv;
    }
    return;
  }

  #pragma unroll
  for (int i = 0; i < 4; i++){
    #pragma unroll
    for (int j = 0; j < 4; j++){
      #pragma unroll
      for (int r = 0; r < 4; r++){
        int m = m0 + wm + i * 16 + ((lane >> 4) << 2) + r;
        int n = n0 + wn + j * 16 + (lane & 15);
        float v = acc[i][j][r] + (bias ? bias[n] : 0.f);
        if (MODE == 0){
          ((float*)C)[(long)m * N + n] = v;
        } else if (MODE == 3){
          ((u16*)C)[(long)z * 524288 + ((long)(n >> 6) * 512 + m) * 64 + (n & 63)] = f2bf(v);
        } else if (MODE == 4){
          ((u16*)C)[(long)z * 524288 + (long)m * 512 + n] = f2bf(v);
        } else if (MODE == 5){
          int mat = n >> 10;
          int np = n & 1023;
          ((u16*)C)[(long)mat * 4194304 +
                    ((long)((m >> 10) * 16 + (np >> 6)) * 1024 + (m & 1023)) * 64 + (np & 63)] = f2bf(v);
        }
      }
    }
  }
}

// ---------------- k_bias: EB[bhl][s][k] = exp2((c2p+p2c)*sB2), 32 bh per pass ----------------
__global__ __launch_bounds__(256, 4) void k_bias(
    const u16* __restrict__ c2p, const u16* __restrict__ p2c,
    const u16* __restrict__ T3, const u16* __restrict__ ixlo_tbl,
    u16* __restrict__ EB, int bhbase)
{
  __shared__ __attribute__((aligned(16))) u16 C2W[8192];   // [64 s][128]
  __shared__ __attribute__((aligned(16))) u16 P2W[8192];   // [64 k][128]
  __shared__ __attribute__((aligned(16))) u16 IDW[128];
  const int flat0 = blockIdx.x;
  const int flat = (flat0 & 7) * 64 + (flat0 >> 3);   // 512 blocks, xcd-chunked
  const int bhl = flat >> 4, sb = flat & 15;
  const int bh = bhbase + bhl;
  const int tid = threadIdx.x, lane = tid & 63, w = tid >> 6;
  const int s0 = sb * 64;
  const u16* c2b = c2p + (long)bh * 524288;
  const u16* p2b = p2c + (long)bh * 524288;
  u16* EBb = EB + ((long)bhl << 20);
  const float sB2 = 0.12751743f;   // log2(e)/sqrt(128)

  const int r2 = tid >> 2;         // s_local 0..63
  const int q2 = tid & 3;          // k quarter
  const int c2key = (r2 & 15) << 4;

  auto STAGEROW = [&](const u16* rowptr, u16* ldsbase, int row){
    const char* src = (const char*)rowptr + (((lane * 4) ^ ((row & 15) << 4)));
    __builtin_amdgcn_global_load_lds((gas_ptr)src, (las_ptr)((char*)ldsbase + row * 256), 4, 0, 0);
  };

  for (int t = 0; t < 16; t++){
    const int k0 = t * 64;
    const int ixlo = (int)ixlo_tbl[sb * 16 + t];
    #pragma unroll
    for (int r = 0; r < 16; r++){
      int row = w * 16 + r;
      STAGEROW(c2b + (long)(s0 + row) * 512 + ixlo, C2W, row);
      STAGEROW(p2b + (long)(k0 + row) * 512 + ixlo, P2W, row);
    }
    if (w == 0){
      int dev = s0 - k0 - 64;
      __builtin_amdgcn_global_load_lds((gas_ptr)((const char*)(T3 + (dev + 1024)) + lane * 4),
                                       (las_ptr)((char*)IDW), 4, 0, 0);
    }
    __syncthreads();

    u16 ov[16];
    #pragma unroll
    for (int c = 0; c < 16; c++){
      int kl = q2 * 16 + c;
      int j = r2 - kl + 64;
      int ix = (int)IDW[j];
      int x = (ix - ixlo) * 2;
      u16 b1 = *(const u16*)((const char*)C2W + r2 * 256 + (x ^ c2key));
      u16 b2 = *(const u16*)((const char*)P2W + kl * 256 + (x ^ ((kl & 15) << 4)));
      ov[c] = f2bf(exp2f((bf2f(b1) + bf2f(b2)) * sB2));
    }
    u16* dst = EBb + (((long)(s0 + r2)) << 10) + k0 + q2 * 16;
    uint4 st0, st1;
    st0.x = (unsigned)ov[0]  | ((unsigned)ov[1]  << 16);
    st0.y = (unsigned)ov[2]  | ((unsigned)ov[3]  << 16);
    st0.z = (unsigned)ov[4]  | ((unsigned)ov[5]  << 16);
    st0.w = (unsigned)ov[6]  | ((unsigned)ov[7]  << 16);
    st1.x = (unsigned)ov[8]  | ((unsigned)ov[9]  << 16);
    st1.y = (unsigned)ov[10] | ((unsigned)ov[11] << 16);
    st1.z = (unsigned)ov[12] | ((unsigned)ov[13] << 16);
    st1.w = (unsigned)ov[14] | ((unsigned)ov[15] << 16);
    *(uint4*)dst = st0;
    *(uint4*)(dst + 8) = st1;
    __syncthreads();
  }
}

// ---------------- k_attn_eb: streaming flash attn, bias pre-exp'd (32 bh) ----------------
// One raw barrier/tile, counted vmcnt; EB staging wave-private. LDS 48KB.
__global__ __launch_bounds__(256, 3) void k_attn_eb(
    const u16* __restrict__ Q, const u16* __restrict__ K, const u16* __restrict__ Vt,
    const u16* __restrict__ EB, u16* __restrict__ ctx, int bhbase)
{
  __shared__ __attribute__((aligned(16))) u16 Ks[2][4096];
  __shared__ __attribute__((aligned(16))) u16 Vs[2][4096];
  __shared__ __attribute__((aligned(16))) u16 EBs[4096];
  __shared__ __attribute__((aligned(16))) u16 Pt[4096];
  const int flat0 = blockIdx.x;
  const int flat = (flat0 & 7) * 64 + (flat0 >> 3);   // 512 blocks, xcd-chunked
  const int bhl = flat >> 4, sb = flat & 15;
  const int bh = bhbase + bhl;
  const int tid = threadIdx.x, lane = tid & 63, w = tid >> 6;
  const int s15 = lane & 15, g = lane >> 4;
  const int s0 = sb * 64;
  const int myrow = w * 16 + s15;
  const int s_row = s0 + myrow;
  const u16* Qb  = Q   + (long)bh * 65536;
  const u16* Kg  = K   + (long)bh * 65536;
  const u16* Vg  = Vt  + (long)bh * 65536;
  const u16* EBg = EB  + ((long)bhl << 20);

  short8_t qf0 = *(const short8_t*)(Qb + (long)s_row * 64 + g * 8);
  short8_t qf1 = *(const short8_t*)(Qb + (long)s_row * 64 + 32 + g * 8);

  const int srow8  = lane >> 3;
  const int schunk = (lane & 7) ^ srow8;
  const float sA2 = 0.10411754f;   // log2(e)/sqrt(192)

  auto STAGE_KV = [&](int buf, int kt){
    #pragma unroll
    for (int ii = 0; ii < 2; ii++){
      int i = w * 2 + ii;
      int row = i * 8 + srow8;
      __builtin_amdgcn_global_load_lds(
        (gas_ptr)((const char*)(Kg + (long)(kt + row) * 64) + schunk * 16),
        (las_ptr)((char*)&Ks[buf][0] + i * 1024), 16, 0, 0);
      __builtin_amdgcn_global_load_lds(
        (gas_ptr)((const char*)(Vg + (long)row * 1024 + kt) + schunk * 16),
        (las_ptr)((char*)&Vs[buf][0] + i * 1024), 16, 0, 0);
    }
  };
  auto STAGE_EB = [&](int kt){
    #pragma unroll
    for (int ii = 0; ii < 2; ii++){
      int rowl = w * 16 + ii * 8 + srow8;
      const char* src = (const char*)(EBg + (((long)(s0 + rowl)) << 10) + kt) + schunk * 16;
      __builtin_amdgcn_global_load_lds((gas_ptr)src,
        (las_ptr)((char*)EBs + (w * 2 + ii) * 1024), 16, 0, 0);
    }
  };

  STAGE_KV(0, 0);   // 4 loads
  STAGE_EB(0);      // 2 loads

  float rowsum = 0.f;
  floatx4 oacc[4];
  #pragma unroll
  for (int dt = 0; dt < 4; dt++) oacc[dt] = (floatx4){0.f, 0.f, 0.f, 0.f};

  const int psw = (myrow & 7) << 4;

  for (int t = 0; t < 16; t++){
    const int buf = t & 1;
    const int kt = t * 64;

    // wait: all but the 2 youngest (EB(t)) done -> KV(t) landed
    asm volatile("s_waitcnt vmcnt(2)" ::: "memory");
    asm volatile("s_waitcnt lgkmcnt(0)" ::: "memory");
    __builtin_amdgcn_s_barrier();   // all waves done reading buf^1; KV(t) in LDS

    STAGE_KV(buf ^ 1, (t < 15) ? kt + 64 : 0);   // 4 loads

    // QK^T swapped: a[T] lane = col s=s15, rows k=T*16+g*4+e
    floatx4 a[4];
    #pragma unroll
    for (int T = 0; T < 4; T++){
      int row = T * 16 + s15;
      const char* rp = (const char*)&Ks[buf][0] + row * 128;
      int sw = (row & 7) << 4;
      short8_t k0v = *(const short8_t*)(rp + ((g * 16) ^ sw));
      short8_t k1v = *(const short8_t*)(rp + ((64 + g * 16) ^ sw));
      floatx4 acc = (floatx4){0.f, 0.f, 0.f, 0.f};
      acc = __builtin_amdgcn_mfma_f32_16x16x32_bf16(k0v, qf0, acc, 0, 0, 0);
      acc = __builtin_amdgcn_mfma_f32_16x16x32_bf16(k1v, qf1, acc, 0, 0, 0);
      a[T] = acc;
    }

    // wait: all but the 4 youngest (KV(t+1)) done -> EB(t) landed
    asm volatile("s_waitcnt vmcnt(4)" ::: "memory");

    #pragma unroll
    for (int T = 0; T < 4; T++){
      uint2 ebv = *(const uint2*)((const char*)EBs + myrow * 128 + ((T * 32 + g * 8) ^ psw));
      float e0 = exp2f(a[T][0] * sA2) * bf2f((u16)(ebv.x & 0xffff));
      float e1 = exp2f(a[T][1] * sA2) * bf2f((u16)(ebv.x >> 16));
      float e2 = exp2f(a[T][2] * sA2) * bf2f((u16)(ebv.y & 0xffff));
      float e3 = exp2f(a[T][3] * sA2) * bf2f((u16)(ebv.y >> 16));
      u16 p0 = f2bf(e0), p1 = f2bf(e1), p2v = f2bf(e2), p3 = f2bf(e3);
      rowsum += (bf2f(p0) + bf2f(p1)) + (bf2f(p2v) + bf2f(p3));
      uint2 pk2;
      pk2.x = (unsigned)p0  | ((unsigned)p1 << 16);
      pk2.y = (unsigned)p2v | ((unsigned)p3 << 16);
      *(uint2*)((char*)Pt + myrow * 128 + ((T * 32 + g * 8) ^ psw)) = pk2;
    }

    // own EB rows consumed; restage for t+1 (wave-private, no barrier)
    asm volatile("s_waitcnt lgkmcnt(0)" ::: "memory");
    STAGE_EB((t < 15) ? kt + 64 : 0);   // 2 loads

    // PV
    #pragma unroll
    for (int M = 0; M < 2; M++){
      short8_t pf = *(const short8_t*)((const char*)Pt + myrow * 128 + ((M * 64 + g * 16) ^ psw));
      #pragma unroll
      for (int dt = 0; dt < 4; dt++){
        int drow = dt * 16 + s15;
        short8_t vf = *(const short8_t*)((const char*)&Vs[buf][0] + drow * 128 + ((M * 64 + g * 16) ^ ((drow & 7) << 4)));
        oacc[dt] = __builtin_amdgcn_mfma_f32_16x16x32_bf16(pf, vf, oacc[dt], 0, 0, 0);
      }
    }
  }

  asm volatile("s_waitcnt vmcnt(0)" ::: "memory");   // drain dummy stages

  rowsum += __shfl_xor(rowsum, 16);
  rowsum += __shfl_xor(rowsum, 32);
  float rinv = 1.f / rowsum;

  const int b = bh >> 4, h = bh & 15;
  #pragma unroll
  for (int r = 0; r < 4; r++){
    float ri = __shfl(rinv, g * 4 + r);
    int s_out = s0 + w * 16 + g * 4 + r;
    #pragma unroll
    for (int dt = 0; dt < 4; dt++){
      long oi = ((long)b * 1024 + s_out) * 1024 + h * 64 + dt * 16 + s15;
      ctx[oi] = f2bf(oacc[dt][r] * ri);
    }
  }
}

// ---------------- fallback: R5 window-staged attention (proven) ----------------
__global__ __launch_bounds__(256, 2) void k_attn_win(
    const u16* __restrict__ Q, const u16* __restrict__ K, const u16* __restrict__ Vt,
    const u16* __restrict__ c2p, const u16* __restrict__ p2c,
    const u16* __restrict__ T3, const u16* __restrict__ ixlo_tbl,
    u16* __restrict__ ctx)
{
  __shared__ __attribute__((aligned(16))) u16 Ks[2][4096];
  __shared__ __attribute__((aligned(16))) u16 Vs[2][4096];
  __shared__ __attribute__((aligned(16))) u16 Pt[4096];
  __shared__ __attribute__((aligned(16))) u16 C2W[8192];
  __shared__ __attribute__((aligned(16))) u16 P2W[8192];
  __shared__ __attribute__((aligned(16))) u16 IDW[4][128];
  const int flat0 = blockIdx.x;
  const int flat = (flat0 & 7) * 128 + (flat0 >> 3);
  const int bh = flat >> 4, sb = flat & 15;
  const int tid = threadIdx.x, lane = tid & 63, w = tid >> 6;
  const int s15 = lane & 15, g = lane >> 4;
  const int s0 = sb * 64;
  const int myrow = w * 16 + s15;
  const int s_row = s0 + myrow;
  const u16* Qb  = Q   + (long)bh * 65536;
  const u16* Kg  = K   + (long)bh * 65536;
  const u16* Vg  = Vt  + (long)bh * 65536;
  const u16* c2b = c2p + (long)bh * 524288;
  const u16* p2b = p2c + (long)bh * 524288;

  short8_t qf0 = *(const short8_t*)(Qb + (long)s_row * 64 + g * 8);
  short8_t qf1 = *(const short8_t*)(Qb + (long)s_row * 64 + 32 + g * 8);

  const int srow8  = lane >> 3;
  const int schunk = (lane & 7) ^ srow8;
  const float sA2 = 0.10411754f;
  const float sB2 = 0.12751743f;

  auto STAGEKV = [&](int buf, int kt){
    #pragma unroll
    for (int ii = 0; ii < 2; ii++){
      int i = w * 2 + ii;
      int row = i * 8 + srow8;
      __builtin_amdgcn_global_load_lds(
        (gas_ptr)((const char*)(Kg + (long)(kt + row) * 64) + schunk * 16),
        (las_ptr)((char*)&Ks[buf][0] + i * 1024), 16, 0, 0);
      __builtin_amdgcn_global_load_lds(
        (gas_ptr)((const char*)(Vg + (long)row * 1024 + kt) + schunk * 16),
        (las_ptr)((char*)&Vs[buf][0] + i * 1024), 16, 0, 0);
    }
  };
  auto STAGEROW = [&](const u16* rowptr, u16* ldsbase, int row){
    const char* src = (const char*)rowptr + (((lane * 4) ^ ((row & 15) << 4)));
    __builtin_amdgcn_global_load_lds((gas_ptr)src, (las_ptr)((char*)ldsbase + row * 256), 4, 0, 0);
  };

  const int tb16 = sb * 16;
  int ixlo_cur = (int)ixlo_tbl[tb16];

  #pragma unroll
  for (int r = 0; r < 16; r++){
    int row = w * 16 + r;
    STAGEROW(p2b + (long)row * 512 + ixlo_cur, P2W, row);
  }
  {
    int dev = s0 - 64;
    __builtin_amdgcn_global_load_lds((gas_ptr)((const char*)(T3 + (dev + 1024)) + lane * 4),
                                     (las_ptr)((char*)IDW + w * 256), 4, 0, 0);
  }
  STAGEKV(0, 0);

  float rowsum = 0.f;
  floatx4 oacc[4];
  #pragma unroll
  for (int dt = 0; dt < 4; dt++) oacc[dt] = (floatx4){0.f, 0.f, 0.f, 0.f};

  const int psw = (myrow & 7) << 4;
  const int c2wkey = (myrow & 15) << 4;

  __syncthreads();

  for (int t = 0; t < 16; t++){
    const int buf = t & 1;
    const int k0 = t * 64;

    int ixlo_next = 0;
    if (t < 15) ixlo_next = (int)ixlo_tbl[tb16 + t + 1];
    if (t < 15) STAGEKV(buf ^ 1, k0 + 64);
    #pragma unroll
    for (int r = 0; r < 16; r++){
      int row = w * 16 + r;
      STAGEROW(c2b + (long)(s0 + row) * 512 + ixlo_cur, C2W, row);
    }

    floatx4 a[4];
    #pragma unroll
    for (int T = 0; T < 4; T++){
      int row = T * 16 + s15;
      const char* rp = (const char*)&Ks[buf][0] + row * 128;
      int sw = (row & 7) << 4;
      short8_t k0v = *(const short8_t*)(rp + ((g * 16) ^ sw));
      short8_t k1v = *(const short8_t*)(rp + ((64 + g * 16) ^ sw));
      floatx4 acc = (floatx4){0.f, 0.f, 0.f, 0.f};
      acc = __builtin_amdgcn_mfma_f32_16x16x32_bf16(k0v, qf0, acc, 0, 0, 0);
      acc = __builtin_amdgcn_mfma_f32_16x16x32_bf16(k1v, qf1, acc, 0, 0, 0);
      a[T] = acc;
    }

    asm volatile("s_waitcnt vmcnt(0)" ::: "memory");

    #pragma unroll
    for (int T = 0; T < 4; T++){
      int klb = T * 16 + g * 4;
      int jb = myrow + 64 - klb;
      u16 pv[4];
      #pragma unroll
      for (int e = 0; e < 4; e++){
        int ix = (int)*(const u16*)((const char*)IDW + w * 256 + (jb - e) * 2);
        int x = (ix - ixlo_cur) * 2;
        int kl = klb + e;
        u16 b1 = *(const u16*)((const char*)C2W + myrow * 256 + (x ^ c2wkey));
        u16 b2 = *(const u16*)((const char*)P2W + kl * 256 + (x ^ ((kl & 15) << 4)));
        float bs = bf2f(b1) + bf2f(b2);
        float ev = exp2f(a[T][e] * sA2 + bs * sB2);
        pv[e] = f2bf(ev);
        rowsum += bf2f(pv[e]);
      }
      uint2 pk2;
      pk2.x = (unsigned)pv[0] | ((unsigned)pv[1] << 16);
      pk2.y = (unsigned)pv[2] | ((unsigned)pv[3] << 16);
      *(uint2*)((char*)Pt + myrow * 128 + ((T * 32 + g * 8) ^ psw)) = pk2;
    }

    __syncthreads();

    if (t < 15){
      #pragma unroll
      for (int r = 0; r < 16; r++){
        int row = w * 16 + r;
        STAGEROW(p2b + (long)(k0 + 64 + row) * 512 + ixlo_next, P2W, row);
      }
      int dev = s0 - (k0 + 64) - 64;
      __builtin_amdgcn_global_load_lds((gas_ptr)((const char*)(T3 + (dev + 1024)) + lane * 4),
                                       (las_ptr)((char*)IDW + w * 256), 4, 0, 0);
    }

    #pragma unroll
    for (int M = 0; M < 2; M++){
      short8_t pf = *(const short8_t*)((const char*)Pt + myrow * 128 + ((M * 64 + g * 16) ^ psw));
      #pragma unroll
      for (int dt = 0; dt < 4; dt++){
        int drow = dt * 16 + s15;
        short8_t vf = *(const short8_t*)((const char*)&Vs[buf][0] + drow * 128 + ((M * 64 + g * 16) ^ ((drow & 7) << 4)));
        oacc[dt] = __builtin_amdgcn_mfma_f32_16x16x32_bf16(pf, vf, oacc[dt], 0, 0, 0);
      }
    }

    ixlo_cur = ixlo_next;
    __syncthreads();
  }

  rowsum += __shfl_xor(rowsum, 16);
  rowsum += __shfl_xor(rowsum, 32);
  float rinv = 1.f / rowsum;

  const int b = bh >> 4, h = bh & 15;
  #pragma unroll
  for (int r = 0; r < 4; r++){
    float ri = __shfl(rinv, g * 4 + r);
    int s_out = s0 + w * 16 + g * 4 + r;
    #pragma unroll
    for (int dt = 0; dt < 4; dt++){
      long oi = ((long)b * 1024 + s_out) * 1024 + h * 64 + dt * 16 + s15;
      ctx[oi] = f2bf(oacc[dt][r] * ri);
    }
  }
}

// ---------------- launch ----------------
extern "C" void kernel_launch(void* const* d_in, const int* in_sizes, int n_in,
                              void* d_out, int out_size, void* d_ws, size_t ws_size,
                              hipStream_t stream){
  const float* hs  = (const float*)d_in[0];
  const float* Wq  = (const float*)d_in[1];
  const float* bq  = (const float*)d_in[2];
  const float* Wk  = (const float*)d_in[3];
  const float* bk  = (const float*)d_in[4];
  const float* Wv  = (const float*)d_in[5];
  const float* bv  = (const float*)d_in[6];
  const float* Wo  = (const float*)d_in[7];
  const float* bo  = (const float*)d_in[8];
  const float* rel = (const float*)d_in[9];
  const float* lng = (const float*)d_in[10];
  const float* lnb = (const float*)d_in[11];
  const float* Wpk = (const float*)d_in[12];
  const float* bpk = (const float*)d_in[13];
  const float* Wpq = (const float*)d_in[14];
  const float* bpq = (const float*)d_in[15];

  char* ws = (char*)d_ws;
  size_t off = 0;
  auto alloc = [&](size_t bytes){ size_t o = off; off += (bytes + 255) & ~(size_t)255; return o; };
  // ---- live-through-end region ----
  u16* Wo_t  = (u16*)(ws + alloc(1048576UL * 2));    // Wo transposed (needed last)
  u16* Qd    = (u16*)(ws + alloc(4194304UL * 2));    // [64bh,1024,64]
  u16* Kd    = (u16*)(ws + alloc(4194304UL * 2));    // adjacent to Qd (MODE4/5 rely on it)
  u16* Vtd   = (u16*)(ws + alloc(4194304UL * 2));    // [64bh,64,1024]
  u16* c2p   = (u16*)(ws + alloc(33554432UL * 2));   // [64bh,1024,512]
  u16* p2c   = (u16*)(ws + alloc(33554432UL * 2));   // adjacent to c2p
  u16* ctx   = (u16*)(ws + alloc(4194304UL * 2));
  u16* idxt  = (u16*)(ws + alloc(2048UL * 2));
  u16* ixlo  = (u16*)(ws + alloc(256UL * 2));
  float* qkvb = (float*)(ws + alloc(3072UL * 4));
  float* posb = (float*)(ws + alloc(2048UL * 4));
  // ---- dead-after-c2p-GEMM region (EB aliases from here) ----
  size_t dead0 = off;
  u16* h_bf  = (u16*)(ws + alloc(4194304UL * 2));    // [4096,1024] bf16
  u16* Wt5   = (u16*)(ws + alloc(5UL * 1048576 * 2));// Wq|Wk|Wv|Wpk|Wpq transposed
  u16* re_bf = (u16*)(ws + alloc(524288UL * 2));
  u16* posk  = (u16*)(ws + alloc(524288UL * 2));     // [16h,512,64]
  u16* posq  = (u16*)(ws + alloc(524288UL * 2));     // adjacent to posk
  u16* EB    = (u16*)(ws + dead0);                   // 32bh x 1024 x 1024 bf16 = 64 MiB
  const size_t need_eb = dead0 + 67108864UL;
  const bool use_eb = (ws_size >= need_eb);
  (void)posq; (void)p2c; (void)Kd;

  k_prep<<<6145, 256, 0, stream>>>(hs, Wq, Wk, Wv, Wpk, Wpq, Wo, rel, lng, lnb,
                                   bq, bk, bv, bpk, bpq,
                                   h_bf, Wt5, Wo_t, re_bf, idxt, ixlo, qkvb, posb);

  // fused QKV projection: N=3072 (Wq|Wk|Wv contiguous in Wt5)
  k_gemm<5><<<dim3(24, 32, 1), 256, 0, stream>>>(h_bf, Wt5, qkvb, Qd, Vtd,
                                                 4096, 3072, 1024, 1024, 1024);
  // posk / posq (z=0/1), B base = Wpk slot
  k_gemm<3><<<dim3(8, 4, 2), 256, 0, stream>>>(re_bf, Wt5 + 3145728, posb, posk, nullptr,
                                               512, 1024, 1024, 1024, 1024);
  // c2p (z<64) / p2c (z>=64), batched over bh
  k_gemm<4><<<dim3(4, 8, 128), 256, 0, stream>>>(Qd, posk, nullptr, c2p, nullptr,
                                                 1024, 512, 64, 64, 64);

  if (use_eb){
    // two bh-halves, stream-serial (implicit barrier between kernels)
    k_bias   <<<dim3(512), 256, 0, stream>>>(c2p, p2c, idxt, ixlo, EB, 0);
    k_attn_eb<<<dim3(512), 256, 0, stream>>>(Qd, Kd, Vtd, EB, ctx, 0);
    k_bias   <<<dim3(512), 256, 0, stream>>>(c2p, p2c, idxt, ixlo, EB, 32);
    k_attn_eb<<<dim3(512), 256, 0, stream>>>(Qd, Kd, Vtd, EB, ctx, 32);
  } else {
    k_attn_win<<<dim3(1024), 256, 0, stream>>>(Qd, Kd, Vtd, c2p, p2c, idxt, ixlo, ctx);
  }

  // output projection (f32 out)
  k_gemm<0><<<dim3(8, 32, 1), 256, 0, stream>>>(ctx, Wo_t, bo, d_out, nullptr,
                                                4096, 1024, 1024, 1024, 1024);
}

// Round 8
// 343.733 us; speedup vs baseline: 1.3214x; 1.3214x over previous
//
#include <hip/hip_runtime.h>

typedef unsigned short u16;
typedef __attribute__((ext_vector_type(8))) short short8_t;
typedef __attribute__((ext_vector_type(4))) float floatx4;

typedef const void __attribute__((address_space(1)))* gas_ptr;
typedef void __attribute__((address_space(3)))* las_ptr;

__device__ __forceinline__ float bf2f(u16 u){
  union { unsigned i; float f; } v; v.i = ((unsigned)u) << 16; return v.f;
}
__device__ __forceinline__ u16 f2bf(float x){
  unsigned u = __float_as_uint(x);
  return (u16)((u + 0x7FFFu + ((u >> 16) & 1u)) >> 16);
}
__device__ __forceinline__ int bucket_idx(int delta){
  int b;
  if (delta >= -128 && delta <= 128) b = delta;
  else {
    float a = (float)(delta < 0 ? -delta : delta);
    float lp = ceilf(logf(a * (1.0f / 128.0f)) / logf(511.0f / 128.0f) * 127.0f) + 128.0f;
    b = (int)lp;
    if (delta < 0) b = -b;
  }
  int idx = b + 256;
  return idx < 0 ? 0 : (idx > 511 ? 511 : idx);
}
__device__ __forceinline__ int win_lo(int s0, int t){
  int dlo = s0 - t * 64 - 63;
  int lo = bucket_idx(dlo) & ~1;
  return lo > 384 ? 384 : lo;
}

// ---------------- fused prep kernel ----------------
__global__ __launch_bounds__(256) void k_prep(
    const float* __restrict__ hs,
    const float* __restrict__ W0, const float* __restrict__ W1, const float* __restrict__ W2,
    const float* __restrict__ W3, const float* __restrict__ W4, const float* __restrict__ W5,
    const float* __restrict__ rel, const float* __restrict__ lng, const float* __restrict__ lnb,
    const float* __restrict__ bq, const float* __restrict__ bk, const float* __restrict__ bv,
    const float* __restrict__ bpk, const float* __restrict__ bpq,
    u16* __restrict__ h_bf, u16* __restrict__ Wt5, u16* __restrict__ Wo_t,
    u16* __restrict__ re_bf, u16* __restrict__ idxt,
    float* __restrict__ qkvb, float* __restrict__ posb)
{
  __shared__ float t[64][65];
  const int bid = blockIdx.x, tid = threadIdx.x;
  if (bid < 4096){
    int i = bid * 256 + tid;
    float4 v = ((const float4*)hs)[i];
    ushort4 o;
    o.x = f2bf(v.x); o.y = f2bf(v.y); o.z = f2bf(v.z); o.w = f2bf(v.w);
    ((ushort4*)h_bf)[i] = o;
  } else if (bid < 5632){
    int b2 = bid - 4096;
    int z = b2 >> 8, rem = b2 & 255;
    const float* W = (z == 0) ? W0 : (z == 1) ? W1 : (z == 2) ? W2 : (z == 3) ? W3 : (z == 4) ? W4 : W5;
    u16* Wt = (z < 5) ? (Wt5 + (long)z * 1048576) : Wo_t;
    int n0 = (rem & 15) * 64, k0 = (rem >> 4) * 64;
    #pragma unroll
    for (int i = 0; i < 16; i++){
      int e = i * 256 + tid; int r = e >> 6, c = e & 63;
      t[r][c] = W[(long)(k0 + r) * 1024 + n0 + c];
    }
    __syncthreads();
    #pragma unroll
    for (int i = 0; i < 16; i++){
      int e = i * 256 + tid; int r = e >> 6, c = e & 63;
      Wt[(long)(n0 + r) * 1024 + k0 + c] = f2bf(t[c][r]);
    }
  } else if (bid < 6144){
    int row = bid - 5632;
    float* red = (float*)t;
    float4 v = ((const float4*)(rel + (long)row * 1024))[tid];
    float s  = v.x + v.y + v.z + v.w;
    float s2 = v.x*v.x + v.y*v.y + v.z*v.z + v.w*v.w;
    #pragma unroll
    for (int o = 1; o < 64; o <<= 1){ s += __shfl_xor(s, o); s2 += __shfl_xor(s2, o); }
    if ((tid & 63) == 0){ red[(tid >> 6) * 2] = s; red[(tid >> 6) * 2 + 1] = s2; }
    __syncthreads();
    s  = red[0] + red[2] + red[4] + red[6];
    s2 = red[1] + red[3] + red[5] + red[7];
    float mu  = s * (1.f / 1024.f);
    float var = s2 * (1.f / 1024.f) - mu * mu;
    float rs  = rsqrtf(var + 1e-5f);
    float4 gg = ((const float4*)lng)[tid];
    float4 bb = ((const float4*)lnb)[tid];
    ushort4 o;
    o.x = f2bf((v.x - mu) * rs * gg.x + bb.x);
    o.y = f2bf((v.y - mu) * rs * gg.y + bb.y);
    o.z = f2bf((v.z - mu) * rs * gg.z + bb.z);
    o.w = f2bf((v.w - mu) * rs * gg.w + bb.w);
    ((ushort4*)(re_bf + (long)row * 1024))[tid] = o;
  } else {
    for (int i = tid; i < 2048; i += 256)
      idxt[i] = (u16)bucket_idx(i - 1024);
    for (int i = tid; i < 1024; i += 256){
      qkvb[i] = bq[i]; qkvb[1024 + i] = bk[i]; qkvb[2048 + i] = bv[i];
      posb[i] = bpk[i]; posb[1024 + i] = bpq[i];
    }
  }
}

// ---------------- MFMA GEMM ----------------
// MODE 0: f32 rowmajor   MODE 3: pos GEMM z in {0,1}
// MODE 4: EC/EP batched z in [0,128): stores exp2(v*sB2)   MODE 5: fused QKV N=3072
template<int MODE>
__global__ __launch_bounds__(256) void k_gemm(
    const u16* __restrict__ A, const u16* __restrict__ Bt,
    const float* __restrict__ bias, void* __restrict__ C, void* __restrict__ C2,
    int M, int N, int K, int lda, int ldb)
{
  __shared__ __attribute__((aligned(16))) u16 smem[16384];
  u16* As = smem;
  u16* Bs = smem + 8192;
  const int z = blockIdx.z;
  const u16* Ab = A;
  const u16* Bb = Bt;
  if (MODE == 3){ Bb = Bt + (long)z * 1048576; bias += z << 10; }
  if (MODE == 4){ Ab = A + (long)z * 65536; Bb = Bt + (long)(z >> 6) * 524288 + (long)(z & 15) * 32768; }
  const int m0 = blockIdx.y * 128, n0 = blockIdx.x * 128;
  const int tid = threadIdx.x, lane = tid & 63, w = tid >> 6;
  const int wm = (w >> 1) * 64, wn = (w & 1) * 64;
  floatx4 acc[4][4];
  #pragma unroll
  for (int i = 0; i < 4; i++)
    #pragma unroll
    for (int j = 0; j < 4; j++) acc[i][j] = (floatx4){0.f, 0.f, 0.f, 0.f};

  const int r8 = lane >> 3;
  const int cswz = ((lane & 7) ^ r8) << 4;

  for (int kt = 0; kt < K; kt += 64){
    #pragma unroll
    for (int c = 0; c < 4; c++){
      int row = (c * 4 + w) * 8 + r8;
      const char* ga = (const char*)(Ab + (long)(m0 + row) * lda + kt) + cswz;
      __builtin_amdgcn_global_load_lds((gas_ptr)ga, (las_ptr)((char*)As + (c * 4 + w) * 1024), 16, 0, 0);
      const char* gb = (const char*)(Bb + (long)(n0 + row) * ldb + kt) + cswz;
      __builtin_amdgcn_global_load_lds((gas_ptr)gb, (las_ptr)((char*)Bs + (c * 4 + w) * 1024), 16, 0, 0);
    }
    __syncthreads();
    short8_t af[2][4], bfr[2][4];
    #pragma unroll
    for (int kk = 0; kk < 2; kk++){
      #pragma unroll
      for (int i = 0; i < 4; i++){
        int ra = wm + i * 16 + (lane & 15);
        af[kk][i] = *(const short8_t*)((const char*)As + ra * 128 + ((kk * 64 + ((lane >> 4) << 4)) ^ ((ra & 7) << 4)));
        int rb = wn + i * 16 + (lane & 15);
        bfr[kk][i] = *(const short8_t*)((const char*)Bs + rb * 128 + ((kk * 64 + ((lane >> 4) << 4)) ^ ((rb & 7) << 4)));
      }
    }
    #pragma unroll
    for (int i = 0; i < 4; i++)
      #pragma unroll
      for (int j = 0; j < 4; j++){
        acc[i][j] = __builtin_amdgcn_mfma_f32_16x16x32_bf16(af[0][i], bfr[0][j], acc[i][j], 0, 0, 0);
        acc[i][j] = __builtin_amdgcn_mfma_f32_16x16x32_bf16(af[1][i], bfr[1][j], acc[i][j], 0, 0, 0);
      }
    __syncthreads();
  }

  if (MODE == 5 && n0 >= 2048){
    #pragma unroll
    for (int i = 0; i < 4; i++){
      #pragma unroll
      for (int j = 0; j < 4; j++){
        #pragma unroll
        for (int r = 0; r < 4; r++){
          int ml = wm + i * 16 + ((lane >> 4) << 2) + r;
          int nl = wn + j * 16 + (lane & 15);
          float v = acc[i][j][r] + bias[n0 + nl];
          int byte_ = nl * 256 + ((ml * 2) ^ ((nl & 7) << 4));
          *(u16*)((char*)smem + byte_) = f2bf(v);
        }
      }
    }
    __syncthreads();
    #pragma unroll
    for (int rr = 0; rr < 8; rr++){
      int nl = rr * 16 + (tid >> 4);
      int np = n0 + nl - 2048;
      int mc = tid & 15;
      short8_t vv = *(const short8_t*)((const char*)smem + nl * 256 + ((mc * 16) ^ ((nl & 7) << 4)));
      int m = m0 + mc * 8;
      long base = ((long)((m >> 10) * 16 + (np >> 6)) * 64 + (np & 63)) * 1024 + (m & 1023);
      *(short8_t*)((u16*)C2 + base) = vv;
    }
    return;
  }

  #pragma unroll
  for (int i = 0; i < 4; i++){
    #pragma unroll
    for (int j = 0; j < 4; j++){
      #pragma unroll
      for (int r = 0; r < 4; r++){
        int m = m0 + wm + i * 16 + ((lane >> 4) << 2) + r;
        int n = n0 + wn + j * 16 + (lane & 15);
        float v = acc[i][j][r] + (bias ? bias[n] : 0.f);
        if (MODE == 0){
          ((float*)C)[(long)m * N + n] = v;
        } else if (MODE == 3){
          ((u16*)C)[(long)z * 524288 + ((long)(n >> 6) * 512 + m) * 64 + (n & 63)] = f2bf(v);
        } else if (MODE == 4){
          // store exp2(v * log2(e)/sqrt(128)) -- EC/EP factorized bias
          ((u16*)C)[(long)z * 524288 + (long)m * 512 + n] = f2bf(exp2f(v * 0.12751743f));
        } else if (MODE == 5){
          int mat = n >> 10;
          int np = n & 1023;
          ((u16*)C)[(long)mat * 4194304 +
                    ((long)((m >> 10) * 16 + (np >> 6)) * 1024 + (m & 1023)) * 64 + (np & 63)] = f2bf(v);
        }
      }
    }
  }
}

// ---------------- k_bias: EB[bhl][s][k] = EC[s][ix] * EP[k][ix] ----------------
// grid nbh*32 (xcd-chunked): (bhl, sb, kq); 8 k-tiles per block.
// Double-buffered windows, one raw barrier/tile, counted vmcnt(2) (stores left outstanding).
__global__ __launch_bounds__(256, 2) void k_bias(
    const u16* __restrict__ EC, const u16* __restrict__ EP,
    const u16* __restrict__ T3, u16* __restrict__ EB, int bhbase)
{
  __shared__ __attribute__((aligned(16))) u16 C2W[2][8192];   // [64 s][128] window
  __shared__ __attribute__((aligned(16))) u16 P2W[2][8192];   // [64 k][128] window
  __shared__ __attribute__((aligned(16))) u16 IDW[2][128];
  const int flat0 = blockIdx.x;
  const int chunk = gridDim.x >> 3;
  const int flat = (flat0 & 7) * chunk + (flat0 >> 3);
  const int bhl = flat >> 5;
  const int sb  = (flat >> 1) & 15;
  const int kq  = flat & 1;
  const int bh = bhbase + bhl;
  const int tid = threadIdx.x, lane = tid & 63, w = tid >> 6;
  const int s0 = sb * 64;
  const u16* c2b = EC + (long)bh * 524288;
  const u16* p2b = EP + (long)bh * 524288;
  u16* EBb = EB + ((long)bhl << 20);

  const int r2 = tid >> 2;         // s_local 0..63
  const int q2 = tid & 3;          // k quarter
  const int c2key = (r2 & 15) << 4;

  auto STAGE = [&](int buf, int t){
    const int ixlo = win_lo(s0, t);   // pure VALU, no memory dependency
    const int k0 = t * 64;
    #pragma unroll
    for (int r = 0; r < 16; r++){
      int row = w * 16 + r;
      const char* sa = (const char*)(c2b + (long)(s0 + row) * 512 + ixlo) + ((lane * 4) ^ ((row & 15) << 4));
      __builtin_amdgcn_global_load_lds((gas_ptr)sa, (las_ptr)((char*)&C2W[buf][0] + row * 256), 4, 0, 0);
      const char* sp = (const char*)(p2b + (long)(k0 + row) * 512 + ixlo) + ((lane * 4) ^ ((row & 15) << 4));
      __builtin_amdgcn_global_load_lds((gas_ptr)sp, (las_ptr)((char*)&P2W[buf][0] + row * 256), 4, 0, 0);
    }
    if (w == 3){
      int dev = s0 - k0 - 64;
      __builtin_amdgcn_global_load_lds((gas_ptr)((const char*)(T3 + (dev + 1024)) + lane * 4),
                                       (las_ptr)((char*)&IDW[buf][0]), 4, 0, 0);
    }
  };

  const int t0 = kq * 8;
  STAGE(0, t0);
  asm volatile("s_waitcnt vmcnt(0)" ::: "memory");
  __builtin_amdgcn_s_barrier();

  for (int i = 0; i < 8; i++){
    const int t = t0 + i, buf = i & 1;
    const int k0 = t * 64;
    const int ixlo = win_lo(s0, t);

    if (i < 7) STAGE(buf ^ 1, t + 1);   // loads for t+1 fly during compute of t

    u16 ov[16];
    #pragma unroll
    for (int c = 0; c < 16; c++){
      int kl = q2 * 16 + c;
      int j = r2 - kl + 64;
      int ix = (int)IDW[buf][j];
      int x = (ix - ixlo) * 2;
      float b1 = bf2f(*(const u16*)((const char*)&C2W[buf][0] + r2 * 256 + (x ^ c2key)));
      float b2 = bf2f(*(const u16*)((const char*)&P2W[buf][0] + kl * 256 + (x ^ ((kl & 15) << 4))));
      ov[c] = f2bf(b1 * b2);
    }
    u16* dst = EBb + (((long)(s0 + r2)) << 10) + k0 + q2 * 16;
    uint4 st0, st1;
    st0.x = (unsigned)ov[0]  | ((unsigned)ov[1]  << 16);
    st0.y = (unsigned)ov[2]  | ((unsigned)ov[3]  << 16);
    st0.z = (unsigned)ov[4]  | ((unsigned)ov[5]  << 16);
    st0.w = (unsigned)ov[6]  | ((unsigned)ov[7]  << 16);
    st1.x = (unsigned)ov[8]  | ((unsigned)ov[9]  << 16);
    st1.y = (unsigned)ov[10] | ((unsigned)ov[11] << 16);
    st1.z = (unsigned)ov[12] | ((unsigned)ov[13] << 16);
    st1.w = (unsigned)ov[14] | ((unsigned)ov[15] << 16);
    *(uint4*)dst = st0;
    *(uint4*)(dst + 8) = st1;

    if (i < 7){
      // leave only the 2 stores outstanding -> all loads for t+1 landed
      asm volatile("s_waitcnt vmcnt(2)" ::: "memory");
      __builtin_amdgcn_s_barrier();
    }
  }
}

// ---------------- k_attn_eb: streaming flash attn, bias pre-exp'd ----------------
__global__ __launch_bounds__(256, 3) void k_attn_eb(
    const u16* __restrict__ Q, const u16* __restrict__ K, const u16* __restrict__ Vt,
    const u16* __restrict__ EB, u16* __restrict__ ctx, int bhbase)
{
  __shared__ __attribute__((aligned(16))) u16 Ks[2][4096];
  __shared__ __attribute__((aligned(16))) u16 Vs[2][4096];
  __shared__ __attribute__((aligned(16))) u16 EBs[4096];
  __shared__ __attribute__((aligned(16))) u16 Pt[4096];
  const int flat0 = blockIdx.x;
  const int chunk = gridDim.x >> 3;
  const int flat = (flat0 & 7) * chunk + (flat0 >> 3);
  const int bhl = flat >> 4, sb = flat & 15;
  const int bh = bhbase + bhl;
  const int tid = threadIdx.x, lane = tid & 63, w = tid >> 6;
  const int s15 = lane & 15, g = lane >> 4;
  const int s0 = sb * 64;
  const int myrow = w * 16 + s15;
  const int s_row = s0 + myrow;
  const u16* Qb  = Q   + (long)bh * 65536;
  const u16* Kg  = K   + (long)bh * 65536;
  const u16* Vg  = Vt  + (long)bh * 65536;
  const u16* EBg = EB  + ((long)bhl << 20);

  short8_t qf0 = *(const short8_t*)(Qb + (long)s_row * 64 + g * 8);
  short8_t qf1 = *(const short8_t*)(Qb + (long)s_row * 64 + 32 + g * 8);

  const int srow8  = lane >> 3;
  const int schunk = (lane & 7) ^ srow8;
  const float sA2 = 0.10411754f;   // log2(e)/sqrt(192)

  auto STAGE_KV = [&](int buf, int kt){
    #pragma unroll
    for (int ii = 0; ii < 2; ii++){
      int i = w * 2 + ii;
      int row = i * 8 + srow8;
      __builtin_amdgcn_global_load_lds(
        (gas_ptr)((const char*)(Kg + (long)(kt + row) * 64) + schunk * 16),
        (las_ptr)((char*)&Ks[buf][0] + i * 1024), 16, 0, 0);
      __builtin_amdgcn_global_load_lds(
        (gas_ptr)((const char*)(Vg + (long)row * 1024 + kt) + schunk * 16),
        (las_ptr)((char*)&Vs[buf][0] + i * 1024), 16, 0, 0);
    }
  };
  auto STAGE_EB = [&](int kt){
    #pragma unroll
    for (int ii = 0; ii < 2; ii++){
      int rowl = w * 16 + ii * 8 + srow8;
      const char* src = (const char*)(EBg + (((long)(s0 + rowl)) << 10) + kt) + schunk * 16;
      __builtin_amdgcn_global_load_lds((gas_ptr)src,
        (las_ptr)((char*)EBs + (w * 2 + ii) * 1024), 16, 0, 0);
    }
  };

  STAGE_KV(0, 0);   // 4 loads
  STAGE_EB(0);      // 2 loads

  float rowsum = 0.f;
  floatx4 oacc[4];
  #pragma unroll
  for (int dt = 0; dt < 4; dt++) oacc[dt] = (floatx4){0.f, 0.f, 0.f, 0.f};

  const int psw = (myrow & 7) << 4;

  for (int t = 0; t < 16; t++){
    const int buf = t & 1;
    const int kt = t * 64;

    asm volatile("s_waitcnt vmcnt(2)" ::: "memory");   // KV(t) landed (EB(t) 2 youngest)
    asm volatile("s_waitcnt lgkmcnt(0)" ::: "memory");
    __builtin_amdgcn_s_barrier();

    STAGE_KV(buf ^ 1, (t < 15) ? kt + 64 : 0);   // 4 loads

    floatx4 a[4];
    #pragma unroll
    for (int T = 0; T < 4; T++){
      int row = T * 16 + s15;
      const char* rp = (const char*)&Ks[buf][0] + row * 128;
      int sw = (row & 7) << 4;
      short8_t k0v = *(const short8_t*)(rp + ((g * 16) ^ sw));
      short8_t k1v = *(const short8_t*)(rp + ((64 + g * 16) ^ sw));
      floatx4 acc = (floatx4){0.f, 0.f, 0.f, 0.f};
      acc = __builtin_amdgcn_mfma_f32_16x16x32_bf16(k0v, qf0, acc, 0, 0, 0);
      acc = __builtin_amdgcn_mfma_f32_16x16x32_bf16(k1v, qf1, acc, 0, 0, 0);
      a[T] = acc;
    }

    asm volatile("s_waitcnt vmcnt(4)" ::: "memory");   // EB(t) landed (KV(t+1) 4 youngest)

    #pragma unroll
    for (int T = 0; T < 4; T++){
      uint2 ebv = *(const uint2*)((const char*)EBs + myrow * 128 + ((T * 32 + g * 8) ^ psw));
      float e0 = exp2f(a[T][0] * sA2) * bf2f((u16)(ebv.x & 0xffff));
      float e1 = exp2f(a[T][1] * sA2) * bf2f((u16)(ebv.x >> 16));
      float e2 = exp2f(a[T][2] * sA2) * bf2f((u16)(ebv.y & 0xffff));
      float e3 = exp2f(a[T][3] * sA2) * bf2f((u16)(ebv.y >> 16));
      u16 p0 = f2bf(e0), p1 = f2bf(e1), p2v = f2bf(e2), p3 = f2bf(e3);
      rowsum += (bf2f(p0) + bf2f(p1)) + (bf2f(p2v) + bf2f(p3));
      uint2 pk2;
      pk2.x = (unsigned)p0  | ((unsigned)p1 << 16);
      pk2.y = (unsigned)p2v | ((unsigned)p3 << 16);
      *(uint2*)((char*)Pt + myrow * 128 + ((T * 32 + g * 8) ^ psw)) = pk2;
    }

    asm volatile("s_waitcnt lgkmcnt(0)" ::: "memory");
    STAGE_EB((t < 15) ? kt + 64 : 0);   // 2 loads (wave-private rows)

    #pragma unroll
    for (int M = 0; M < 2; M++){
      short8_t pf = *(const short8_t*)((const char*)Pt + myrow * 128 + ((M * 64 + g * 16) ^ psw));
      #pragma unroll
      for (int dt = 0; dt < 4; dt++){
        int drow = dt * 16 + s15;
        short8_t vf = *(const short8_t*)((const char*)&Vs[buf][0] + drow * 128 + ((M * 64 + g * 16) ^ ((drow & 7) << 4)));
        oacc[dt] = __builtin_amdgcn_mfma_f32_16x16x32_bf16(pf, vf, oacc[dt], 0, 0, 0);
      }
    }
  }

  asm volatile("s_waitcnt vmcnt(0)" ::: "memory");

  rowsum += __shfl_xor(rowsum, 16);
  rowsum += __shfl_xor(rowsum, 32);
  float rinv = 1.f / rowsum;

  const int b = bh >> 4, h = bh & 15;
  #pragma unroll
  for (int r = 0; r < 4; r++){
    float ri = __shfl(rinv, g * 4 + r);
    int s_out = s0 + w * 16 + g * 4 + r;
    #pragma unroll
    for (int dt = 0; dt < 4; dt++){
      long oi = ((long)b * 1024 + s_out) * 1024 + h * 64 + dt * 16 + s15;
      ctx[oi] = f2bf(oacc[dt][r] * ri);
    }
  }
}

// ---------------- launch ----------------
extern "C" void kernel_launch(void* const* d_in, const int* in_sizes, int n_in,
                              void* d_out, int out_size, void* d_ws, size_t ws_size,
                              hipStream_t stream){
  const float* hs  = (const float*)d_in[0];
  const float* Wq  = (const float*)d_in[1];
  const float* bq  = (const float*)d_in[2];
  const float* Wk  = (const float*)d_in[3];
  const float* bk  = (const float*)d_in[4];
  const float* Wv  = (const float*)d_in[5];
  const float* bv  = (const float*)d_in[6];
  const float* Wo  = (const float*)d_in[7];
  const float* bo  = (const float*)d_in[8];
  const float* rel = (const float*)d_in[9];
  const float* lng = (const float*)d_in[10];
  const float* lnb = (const float*)d_in[11];
  const float* Wpk = (const float*)d_in[12];
  const float* bpk = (const float*)d_in[13];
  const float* Wpq = (const float*)d_in[14];
  const float* bpq = (const float*)d_in[15];

  char* ws = (char*)d_ws;
  size_t off = 0;
  auto alloc = [&](size_t bytes){ size_t o = off; off += (bytes + 255) & ~(size_t)255; return o; };
  // ---- live-through-end region ----
  u16* Wo_t  = (u16*)(ws + alloc(1048576UL * 2));
  u16* Qd    = (u16*)(ws + alloc(4194304UL * 2));
  u16* Kd    = (u16*)(ws + alloc(4194304UL * 2));    // adjacent to Qd
  u16* Vtd   = (u16*)(ws + alloc(4194304UL * 2));
  u16* ECd   = (u16*)(ws + alloc(33554432UL * 2));   // exp2(sB2*c2p)
  u16* EPd   = (u16*)(ws + alloc(33554432UL * 2));   // adjacent: exp2(sB2*p2c)
  u16* ctx   = (u16*)(ws + alloc(4194304UL * 2));
  u16* idxt  = (u16*)(ws + alloc(2048UL * 2));
  float* qkvb = (float*)(ws + alloc(3072UL * 4));
  float* posb = (float*)(ws + alloc(2048UL * 4));
  // ---- dead-after-EC/EP-GEMM region (EB aliases from here) ----
  size_t dead0 = off;
  u16* h_bf  = (u16*)(ws + alloc(4194304UL * 2));
  u16* Wt5   = (u16*)(ws + alloc(5UL * 1048576 * 2));
  u16* re_bf = (u16*)(ws + alloc(524288UL * 2));
  u16* posk  = (u16*)(ws + alloc(524288UL * 2));
  u16* posq  = (u16*)(ws + alloc(524288UL * 2));
  u16* EB    = (u16*)(ws + dead0);
  const bool full = (ws_size >= dead0 + 134217728UL);   // 64bh EB fits?
  (void)posq; (void)Kd;

  k_prep<<<6145, 256, 0, stream>>>(hs, Wq, Wk, Wv, Wpk, Wpq, Wo, rel, lng, lnb,
                                   bq, bk, bv, bpk, bpq,
                                   h_bf, Wt5, Wo_t, re_bf, idxt, qkvb, posb);

  // fused QKV projection: N=3072 (Wq|Wk|Wv contiguous in Wt5)
  k_gemm<5><<<dim3(24, 32, 1), 256, 0, stream>>>(h_bf, Wt5, qkvb, Qd, Vtd,
                                                 4096, 3072, 1024, 1024, 1024);
  // posk / posq (z=0/1), B base = Wpk slot
  k_gemm<3><<<dim3(8, 4, 2), 256, 0, stream>>>(re_bf, Wt5 + 3145728, posb, posk, nullptr,
                                               512, 1024, 1024, 1024, 1024);
  // EC (z<64) / EP (z>=64), batched over bh; epilogue applies exp2
  k_gemm<4><<<dim3(4, 8, 128), 256, 0, stream>>>(Qd, posk, nullptr, ECd, nullptr,
                                                 1024, 512, 64, 64, 64);

  if (full){
    k_bias   <<<dim3(2048), 256, 0, stream>>>(ECd, EPd, idxt, EB, 0);
    k_attn_eb<<<dim3(1024), 256, 0, stream>>>(Qd, Kd, Vtd, EB, ctx, 0);
  } else {
    k_bias   <<<dim3(1024), 256, 0, stream>>>(ECd, EPd, idxt, EB, 0);
    k_attn_eb<<<dim3(512),  256, 0, stream>>>(Qd, Kd, Vtd, EB, ctx, 0);
    k_bias   <<<dim3(1024), 256, 0, stream>>>(ECd, EPd, idxt, EB, 32);
    k_attn_eb<<<dim3(512),  256, 0, stream>>>(Qd, Kd, Vtd, EB, ctx, 32);
  }

  // output projection (f32 out)
  k_gemm<0><<<dim3(8, 32, 1), 256, 0, stream>>>(ctx, Wo_t, bo, d_out, nullptr,
                                                4096, 1024, 1024, 1024, 1024);
}

// Round 9
// 300.248 us; speedup vs baseline: 1.5128x; 1.1448x over previous
//
#include <hip/hip_runtime.h>

typedef unsigned short u16;
typedef __attribute__((ext_vector_type(8))) short short8_t;
typedef __attribute__((ext_vector_type(4))) float floatx4;

typedef const void __attribute__((address_space(1)))* gas_ptr;
typedef void __attribute__((address_space(3)))* las_ptr;

__device__ __forceinline__ float bf2f(u16 u){
  union { unsigned i; float f; } v; v.i = ((unsigned)u) << 16; return v.f;
}
__device__ __forceinline__ u16 f2bf(float x){
  unsigned u = __float_as_uint(x);
  return (u16)((u + 0x7FFFu + ((u >> 16) & 1u)) >> 16);
}
__device__ __forceinline__ int bucket_idx(int delta){
  int b;
  if (delta >= -128 && delta <= 128) b = delta;
  else {
    float a = (float)(delta < 0 ? -delta : delta);
    float lp = ceilf(logf(a * (1.0f / 128.0f)) / logf(511.0f / 128.0f) * 127.0f) + 128.0f;
    b = (int)lp;
    if (delta < 0) b = -b;
  }
  int idx = b + 256;
  return idx < 0 ? 0 : (idx > 511 ? 511 : idx);
}
__device__ __forceinline__ int win_lo(int s0, int t){
  int dlo = s0 - t * 64 - 63;
  int lo = bucket_idx(dlo) & ~1;
  return lo > 384 ? 384 : lo;
}

// ---------------- fused prep kernel ----------------
__global__ __launch_bounds__(256) void k_prep(
    const float* __restrict__ hs,
    const float* __restrict__ W0, const float* __restrict__ W1, const float* __restrict__ W2,
    const float* __restrict__ W3, const float* __restrict__ W4, const float* __restrict__ W5,
    const float* __restrict__ rel, const float* __restrict__ lng, const float* __restrict__ lnb,
    const float* __restrict__ bq, const float* __restrict__ bk, const float* __restrict__ bv,
    const float* __restrict__ bpk, const float* __restrict__ bpq,
    u16* __restrict__ h_bf, u16* __restrict__ Wt5, u16* __restrict__ Wo_t,
    u16* __restrict__ re_bf, u16* __restrict__ idxt,
    float* __restrict__ qkvb, float* __restrict__ posb)
{
  __shared__ float t[64][65];
  const int bid = blockIdx.x, tid = threadIdx.x;
  if (bid < 4096){
    int i = bid * 256 + tid;
    float4 v = ((const float4*)hs)[i];
    ushort4 o;
    o.x = f2bf(v.x); o.y = f2bf(v.y); o.z = f2bf(v.z); o.w = f2bf(v.w);
    ((ushort4*)h_bf)[i] = o;
  } else if (bid < 5632){
    int b2 = bid - 4096;
    int z = b2 >> 8, rem = b2 & 255;
    const float* W = (z == 0) ? W0 : (z == 1) ? W1 : (z == 2) ? W2 : (z == 3) ? W3 : (z == 4) ? W4 : W5;
    u16* Wt = (z < 5) ? (Wt5 + (long)z * 1048576) : Wo_t;
    int n0 = (rem & 15) * 64, k0 = (rem >> 4) * 64;
    #pragma unroll
    for (int i = 0; i < 16; i++){
      int e = i * 256 + tid; int r = e >> 6, c = e & 63;
      t[r][c] = W[(long)(k0 + r) * 1024 + n0 + c];
    }
    __syncthreads();
    #pragma unroll
    for (int i = 0; i < 16; i++){
      int e = i * 256 + tid; int r = e >> 6, c = e & 63;
      Wt[(long)(n0 + r) * 1024 + k0 + c] = f2bf(t[c][r]);
    }
  } else if (bid < 6144){
    int row = bid - 5632;
    float* red = (float*)t;
    float4 v = ((const float4*)(rel + (long)row * 1024))[tid];
    float s  = v.x + v.y + v.z + v.w;
    float s2 = v.x*v.x + v.y*v.y + v.z*v.z + v.w*v.w;
    #pragma unroll
    for (int o = 1; o < 64; o <<= 1){ s += __shfl_xor(s, o); s2 += __shfl_xor(s2, o); }
    if ((tid & 63) == 0){ red[(tid >> 6) * 2] = s; red[(tid >> 6) * 2 + 1] = s2; }
    __syncthreads();
    s  = red[0] + red[2] + red[4] + red[6];
    s2 = red[1] + red[3] + red[5] + red[7];
    float mu  = s * (1.f / 1024.f);
    float var = s2 * (1.f / 1024.f) - mu * mu;
    float rs  = rsqrtf(var + 1e-5f);
    float4 gg = ((const float4*)lng)[tid];
    float4 bb = ((const float4*)lnb)[tid];
    ushort4 o;
    o.x = f2bf((v.x - mu) * rs * gg.x + bb.x);
    o.y = f2bf((v.y - mu) * rs * gg.y + bb.y);
    o.z = f2bf((v.z - mu) * rs * gg.z + bb.z);
    o.w = f2bf((v.w - mu) * rs * gg.w + bb.w);
    ((ushort4*)(re_bf + (long)row * 1024))[tid] = o;
  } else {
    for (int i = tid; i < 2048; i += 256)
      idxt[i] = (u16)bucket_idx(i - 1024);
    for (int i = tid; i < 1024; i += 256){
      qkvb[i] = bq[i]; qkvb[1024 + i] = bk[i]; qkvb[2048 + i] = bv[i];
      posb[i] = bpk[i]; posb[1024 + i] = bpq[i];
    }
  }
}

// ---------------- MFMA GEMM ----------------
// MODE 0: f32 rowmajor   MODE 3: pos GEMM z in {0,1}
// MODE 4: EC/EP batched z in [0,128): stores exp2(v*sB2) via LDS-bounce coalesced
// MODE 5: fused QKV N=3072
template<int MODE>
__global__ __launch_bounds__(256) void k_gemm(
    const u16* __restrict__ A, const u16* __restrict__ Bt,
    const float* __restrict__ bias, void* __restrict__ C, void* __restrict__ C2,
    int M, int N, int K, int lda, int ldb)
{
  __shared__ __attribute__((aligned(16))) u16 smem[16384];
  u16* As = smem;
  u16* Bs = smem + 8192;
  const int z = blockIdx.z;
  const u16* Ab = A;
  const u16* Bb = Bt;
  if (MODE == 3){ Bb = Bt + (long)z * 1048576; bias += z << 10; }
  if (MODE == 4){ Ab = A + (long)z * 65536; Bb = Bt + (long)(z >> 6) * 524288 + (long)(z & 15) * 32768; }
  const int m0 = blockIdx.y * 128, n0 = blockIdx.x * 128;
  const int tid = threadIdx.x, lane = tid & 63, w = tid >> 6;
  const int wm = (w >> 1) * 64, wn = (w & 1) * 64;
  floatx4 acc[4][4];
  #pragma unroll
  for (int i = 0; i < 4; i++)
    #pragma unroll
    for (int j = 0; j < 4; j++) acc[i][j] = (floatx4){0.f, 0.f, 0.f, 0.f};

  const int r8 = lane >> 3;
  const int cswz = ((lane & 7) ^ r8) << 4;

  for (int kt = 0; kt < K; kt += 64){
    #pragma unroll
    for (int c = 0; c < 4; c++){
      int row = (c * 4 + w) * 8 + r8;
      const char* ga = (const char*)(Ab + (long)(m0 + row) * lda + kt) + cswz;
      __builtin_amdgcn_global_load_lds((gas_ptr)ga, (las_ptr)((char*)As + (c * 4 + w) * 1024), 16, 0, 0);
      const char* gb = (const char*)(Bb + (long)(n0 + row) * ldb + kt) + cswz;
      __builtin_amdgcn_global_load_lds((gas_ptr)gb, (las_ptr)((char*)Bs + (c * 4 + w) * 1024), 16, 0, 0);
    }
    __syncthreads();
    short8_t af[2][4], bfr[2][4];
    #pragma unroll
    for (int kk = 0; kk < 2; kk++){
      #pragma unroll
      for (int i = 0; i < 4; i++){
        int ra = wm + i * 16 + (lane & 15);
        af[kk][i] = *(const short8_t*)((const char*)As + ra * 128 + ((kk * 64 + ((lane >> 4) << 4)) ^ ((ra & 7) << 4)));
        int rb = wn + i * 16 + (lane & 15);
        bfr[kk][i] = *(const short8_t*)((const char*)Bs + rb * 128 + ((kk * 64 + ((lane >> 4) << 4)) ^ ((rb & 7) << 4)));
      }
    }
    #pragma unroll
    for (int i = 0; i < 4; i++)
      #pragma unroll
      for (int j = 0; j < 4; j++){
        acc[i][j] = __builtin_amdgcn_mfma_f32_16x16x32_bf16(af[0][i], bfr[0][j], acc[i][j], 0, 0, 0);
        acc[i][j] = __builtin_amdgcn_mfma_f32_16x16x32_bf16(af[1][i], bfr[1][j], acc[i][j], 0, 0, 0);
      }
    __syncthreads();
  }

  if (MODE == 4){
    // exp2 + bf16 into LDS (swizzled), then coalesced short8 row stores
    #pragma unroll
    for (int i = 0; i < 4; i++){
      #pragma unroll
      for (int j = 0; j < 4; j++){
        #pragma unroll
        for (int r = 0; r < 4; r++){
          int ml = wm + i * 16 + ((lane >> 4) << 2) + r;
          int nl = wn + j * 16 + (lane & 15);
          int byte_ = ml * 256 + ((nl * 2) ^ ((ml & 7) << 4));
          *(u16*)((char*)smem + byte_) = f2bf(exp2f(acc[i][j][r] * 0.12751743f));
        }
      }
    }
    __syncthreads();
    const int row16 = tid >> 4, cch = tid & 15;
    #pragma unroll
    for (int rr = 0; rr < 8; rr++){
      int ml = rr * 16 + row16;
      short8_t vv = *(const short8_t*)((const char*)smem + ml * 256 + ((cch * 16) ^ ((ml & 7) << 4)));
      *(short8_t*)((u16*)C + (long)z * 524288 + (long)(m0 + ml) * 512 + n0 + cch * 8) = vv;
    }
    return;
  }

  if (MODE == 5 && n0 >= 2048){
    #pragma unroll
    for (int i = 0; i < 4; i++){
      #pragma unroll
      for (int j = 0; j < 4; j++){
        #pragma unroll
        for (int r = 0; r < 4; r++){
          int ml = wm + i * 16 + ((lane >> 4) << 2) + r;
          int nl = wn + j * 16 + (lane & 15);
          float v = acc[i][j][r] + bias[n0 + nl];
          int byte_ = nl * 256 + ((ml * 2) ^ ((nl & 7) << 4));
          *(u16*)((char*)smem + byte_) = f2bf(v);
        }
      }
    }
    __syncthreads();
    #pragma unroll
    for (int rr = 0; rr < 8; rr++){
      int nl = rr * 16 + (tid >> 4);
      int np = n0 + nl - 2048;
      int mc = tid & 15;
      short8_t vv = *(const short8_t*)((const char*)smem + nl * 256 + ((mc * 16) ^ ((nl & 7) << 4)));
      int m = m0 + mc * 8;
      long base = ((long)((m >> 10) * 16 + (np >> 6)) * 64 + (np & 63)) * 1024 + (m & 1023);
      *(short8_t*)((u16*)C2 + base) = vv;
    }
    return;
  }

  #pragma unroll
  for (int i = 0; i < 4; i++){
    #pragma unroll
    for (int j = 0; j < 4; j++){
      #pragma unroll
      for (int r = 0; r < 4; r++){
        int m = m0 + wm + i * 16 + ((lane >> 4) << 2) + r;
        int n = n0 + wn + j * 16 + (lane & 15);
        float v = acc[i][j][r] + (bias ? bias[n] : 0.f);
        if (MODE == 0){
          ((float*)C)[(long)m * N + n] = v;
        } else if (MODE == 3){
          ((u16*)C)[(long)z * 524288 + ((long)(n >> 6) * 512 + m) * 64 + (n & 63)] = f2bf(v);
        } else if (MODE == 5){
          int mat = n >> 10;
          int np = n & 1023;
          ((u16*)C)[(long)mat * 4194304 +
                    ((long)((m >> 10) * 16 + (np >> 6)) * 1024 + (m & 1023)) * 64 + (np & 63)] = f2bf(v);
        }
      }
    }
  }
}

// ---------------- k_bias: EB[bhl][s][k] = EC[s][ix] * EP[k][ix] ----------------
__global__ __launch_bounds__(256, 2) void k_bias(
    const u16* __restrict__ EC, const u16* __restrict__ EP,
    const u16* __restrict__ T3, u16* __restrict__ EB, int bhbase)
{
  __shared__ __attribute__((aligned(16))) u16 C2W[2][8192];
  __shared__ __attribute__((aligned(16))) u16 P2W[2][8192];
  __shared__ __attribute__((aligned(16))) u16 IDW[2][128];
  const int flat0 = blockIdx.x;
  const int chunk = gridDim.x >> 3;
  const int flat = (flat0 & 7) * chunk + (flat0 >> 3);
  const int bhl = flat >> 5;
  const int sb  = (flat >> 1) & 15;
  const int kq  = flat & 1;
  const int bh = bhbase + bhl;
  const int tid = threadIdx.x, lane = tid & 63, w = tid >> 6;
  const int s0 = sb * 64;
  const u16* c2b = EC + (long)bh * 524288;
  const u16* p2b = EP + (long)bh * 524288;
  u16* EBb = EB + ((long)bhl << 20);

  const int r2 = tid >> 2;
  const int q2 = tid & 3;
  const int c2key = (r2 & 15) << 4;

  auto STAGE = [&](int buf, int t){
    const int ixlo = win_lo(s0, t);
    const int k0 = t * 64;
    #pragma unroll
    for (int r = 0; r < 16; r++){
      int row = w * 16 + r;
      const char* sa = (const char*)(c2b + (long)(s0 + row) * 512 + ixlo) + ((lane * 4) ^ ((row & 15) << 4));
      __builtin_amdgcn_global_load_lds((gas_ptr)sa, (las_ptr)((char*)&C2W[buf][0] + row * 256), 4, 0, 0);
      const char* sp = (const char*)(p2b + (long)(k0 + row) * 512 + ixlo) + ((lane * 4) ^ ((row & 15) << 4));
      __builtin_amdgcn_global_load_lds((gas_ptr)sp, (las_ptr)((char*)&P2W[buf][0] + row * 256), 4, 0, 0);
    }
    if (w == 3){
      int dev = s0 - k0 - 64;
      __builtin_amdgcn_global_load_lds((gas_ptr)((const char*)(T3 + (dev + 1024)) + lane * 4),
                                       (las_ptr)((char*)&IDW[buf][0]), 4, 0, 0);
    }
  };

  const int t0 = kq * 8;
  STAGE(0, t0);
  asm volatile("s_waitcnt vmcnt(0)" ::: "memory");
  __builtin_amdgcn_s_barrier();

  for (int i = 0; i < 8; i++){
    const int t = t0 + i, buf = i & 1;
    const int k0 = t * 64;
    const int ixlo = win_lo(s0, t);

    if (i < 7) STAGE(buf ^ 1, t + 1);

    u16 ov[16];
    #pragma unroll
    for (int c = 0; c < 16; c++){
      int kl = q2 * 16 + c;
      int j = r2 - kl + 64;
      int ix = (int)IDW[buf][j];
      int x = (ix - ixlo) * 2;
      float b1 = bf2f(*(const u16*)((const char*)&C2W[buf][0] + r2 * 256 + (x ^ c2key)));
      float b2 = bf2f(*(const u16*)((const char*)&P2W[buf][0] + kl * 256 + (x ^ ((kl & 15) << 4))));
      ov[c] = f2bf(b1 * b2);
    }
    u16* dst = EBb + (((long)(s0 + r2)) << 10) + k0 + q2 * 16;
    uint4 st0, st1;
    st0.x = (unsigned)ov[0]  | ((unsigned)ov[1]  << 16);
    st0.y = (unsigned)ov[2]  | ((unsigned)ov[3]  << 16);
    st0.z = (unsigned)ov[4]  | ((unsigned)ov[5]  << 16);
    st0.w = (unsigned)ov[6]  | ((unsigned)ov[7]  << 16);
    st1.x = (unsigned)ov[8]  | ((unsigned)ov[9]  << 16);
    st1.y = (unsigned)ov[10] | ((unsigned)ov[11] << 16);
    st1.z = (unsigned)ov[12] | ((unsigned)ov[13] << 16);
    st1.w = (unsigned)ov[14] | ((unsigned)ov[15] << 16);
    *(uint4*)dst = st0;
    *(uint4*)(dst + 8) = st1;

    if (i < 7){
      asm volatile("s_waitcnt vmcnt(2)" ::: "memory");
      __builtin_amdgcn_s_barrier();
    }
  }
}

// ---------------- k_attn_eb: streaming flash attn, bias pre-exp'd ----------------
__global__ __launch_bounds__(256, 3) void k_attn_eb(
    const u16* __restrict__ Q, const u16* __restrict__ K, const u16* __restrict__ Vt,
    const u16* __restrict__ EB, u16* __restrict__ ctx, int bhbase)
{
  __shared__ __attribute__((aligned(16))) u16 Ks[2][4096];
  __shared__ __attribute__((aligned(16))) u16 Vs[2][4096];
  __shared__ __attribute__((aligned(16))) u16 EBs[4096];
  __shared__ __attribute__((aligned(16))) u16 Pt[4096];
  const int flat0 = blockIdx.x;
  const int chunk = gridDim.x >> 3;
  const int flat = (flat0 & 7) * chunk + (flat0 >> 3);
  const int bhl = flat >> 4, sb = flat & 15;
  const int bh = bhbase + bhl;
  const int tid = threadIdx.x, lane = tid & 63, w = tid >> 6;
  const int s15 = lane & 15, g = lane >> 4;
  const int s0 = sb * 64;
  const int myrow = w * 16 + s15;
  const int s_row = s0 + myrow;
  const u16* Qb  = Q   + (long)bh * 65536;
  const u16* Kg  = K   + (long)bh * 65536;
  const u16* Vg  = Vt  + (long)bh * 65536;
  const u16* EBg = EB  + ((long)bhl << 20);

  short8_t qf0 = *(const short8_t*)(Qb + (long)s_row * 64 + g * 8);
  short8_t qf1 = *(const short8_t*)(Qb + (long)s_row * 64 + 32 + g * 8);

  const int srow8  = lane >> 3;
  const int schunk = (lane & 7) ^ srow8;
  const float sA2 = 0.10411754f;   // log2(e)/sqrt(192)

  auto STAGE_KV = [&](int buf, int kt){
    #pragma unroll
    for (int ii = 0; ii < 2; ii++){
      int i = w * 2 + ii;
      int row = i * 8 + srow8;
      __builtin_amdgcn_global_load_lds(
        (gas_ptr)((const char*)(Kg + (long)(kt + row) * 64) + schunk * 16),
        (las_ptr)((char*)&Ks[buf][0] + i * 1024), 16, 0, 0);
      __builtin_amdgcn_global_load_lds(
        (gas_ptr)((const char*)(Vg + (long)row * 1024 + kt) + schunk * 16),
        (las_ptr)((char*)&Vs[buf][0] + i * 1024), 16, 0, 0);
    }
  };
  auto STAGE_EB = [&](int kt){
    #pragma unroll
    for (int ii = 0; ii < 2; ii++){
      int rowl = w * 16 + ii * 8 + srow8;
      const char* src = (const char*)(EBg + (((long)(s0 + rowl)) << 10) + kt) + schunk * 16;
      __builtin_amdgcn_global_load_lds((gas_ptr)src,
        (las_ptr)((char*)EBs + (w * 2 + ii) * 1024), 16, 0, 0);
    }
  };

  STAGE_KV(0, 0);
  STAGE_EB(0);

  float rowsum = 0.f;
  floatx4 oacc[4];
  #pragma unroll
  for (int dt = 0; dt < 4; dt++) oacc[dt] = (floatx4){0.f, 0.f, 0.f, 0.f};

  const int psw = (myrow & 7) << 4;

  for (int t = 0; t < 16; t++){
    const int buf = t & 1;
    const int kt = t * 64;

    asm volatile("s_waitcnt vmcnt(2)" ::: "memory");
    asm volatile("s_waitcnt lgkmcnt(0)" ::: "memory");
    __builtin_amdgcn_s_barrier();

    STAGE_KV(buf ^ 1, (t < 15) ? kt + 64 : 0);

    floatx4 a[4];
    #pragma unroll
    for (int T = 0; T < 4; T++){
      int row = T * 16 + s15;
      const char* rp = (const char*)&Ks[buf][0] + row * 128;
      int sw = (row & 7) << 4;
      short8_t k0v = *(const short8_t*)(rp + ((g * 16) ^ sw));
      short8_t k1v = *(const short8_t*)(rp + ((64 + g * 16) ^ sw));
      floatx4 acc = (floatx4){0.f, 0.f, 0.f, 0.f};
      acc = __builtin_amdgcn_mfma_f32_16x16x32_bf16(k0v, qf0, acc, 0, 0, 0);
      acc = __builtin_amdgcn_mfma_f32_16x16x32_bf16(k1v, qf1, acc, 0, 0, 0);
      a[T] = acc;
    }

    asm volatile("s_waitcnt vmcnt(4)" ::: "memory");

    #pragma unroll
    for (int T = 0; T < 4; T++){
      uint2 ebv = *(const uint2*)((const char*)EBs + myrow * 128 + ((T * 32 + g * 8) ^ psw));
      float e0 = exp2f(a[T][0] * sA2) * bf2f((u16)(ebv.x & 0xffff));
      float e1 = exp2f(a[T][1] * sA2) * bf2f((u16)(ebv.x >> 16));
      float e2 = exp2f(a[T][2] * sA2) * bf2f((u16)(ebv.y & 0xffff));
      float e3 = exp2f(a[T][3] * sA2) * bf2f((u16)(ebv.y >> 16));
      u16 p0 = f2bf(e0), p1 = f2bf(e1), p2v = f2bf(e2), p3 = f2bf(e3);
      rowsum += (bf2f(p0) + bf2f(p1)) + (bf2f(p2v) + bf2f(p3));
      uint2 pk2;
      pk2.x = (unsigned)p0  | ((unsigned)p1 << 16);
      pk2.y = (unsigned)p2v | ((unsigned)p3 << 16);
      *(uint2*)((char*)Pt + myrow * 128 + ((T * 32 + g * 8) ^ psw)) = pk2;
    }

    asm volatile("s_waitcnt lgkmcnt(0)" ::: "memory");
    STAGE_EB((t < 15) ? kt + 64 : 0);

    #pragma unroll
    for (int M = 0; M < 2; M++){
      short8_t pf = *(const short8_t*)((const char*)Pt + myrow * 128 + ((M * 64 + g * 16) ^ psw));
      #pragma unroll
      for (int dt = 0; dt < 4; dt++){
        int drow = dt * 16 + s15;
        short8_t vf = *(const short8_t*)((const char*)&Vs[buf][0] + drow * 128 + ((M * 64 + g * 16) ^ ((drow & 7) << 4)));
        oacc[dt] = __builtin_amdgcn_mfma_f32_16x16x32_bf16(pf, vf, oacc[dt], 0, 0, 0);
      }
    }
  }

  asm volatile("s_waitcnt vmcnt(0)" ::: "memory");

  rowsum += __shfl_xor(rowsum, 16);
  rowsum += __shfl_xor(rowsum, 32);
  float rinv = 1.f / rowsum;

  const int b = bh >> 4, h = bh & 15;
  #pragma unroll
  for (int r = 0; r < 4; r++){
    float ri = __shfl(rinv, g * 4 + r);
    int s_out = s0 + w * 16 + g * 4 + r;
    #pragma unroll
    for (int dt = 0; dt < 4; dt++){
      long oi = ((long)b * 1024 + s_out) * 1024 + h * 64 + dt * 16 + s15;
      ctx[oi] = f2bf(oacc[dt][r] * ri);
    }
  }
}

// ---------------- launch ----------------
extern "C" void kernel_launch(void* const* d_in, const int* in_sizes, int n_in,
                              void* d_out, int out_size, void* d_ws, size_t ws_size,
                              hipStream_t stream){
  const float* hs  = (const float*)d_in[0];
  const float* Wq  = (const float*)d_in[1];
  const float* bq  = (const float*)d_in[2];
  const float* Wk  = (const float*)d_in[3];
  const float* bk  = (const float*)d_in[4];
  const float* Wv  = (const float*)d_in[5];
  const float* bv  = (const float*)d_in[6];
  const float* Wo  = (const float*)d_in[7];
  const float* bo  = (const float*)d_in[8];
  const float* rel = (const float*)d_in[9];
  const float* lng = (const float*)d_in[10];
  const float* lnb = (const float*)d_in[11];
  const float* Wpk = (const float*)d_in[12];
  const float* bpk = (const float*)d_in[13];
  const float* Wpq = (const float*)d_in[14];
  const float* bpq = (const float*)d_in[15];

  char* ws = (char*)d_ws;
  size_t off = 0;
  auto alloc = [&](size_t bytes){ size_t o = off; off += (bytes + 255) & ~(size_t)255; return o; };
  // ---- live-through-end region ----
  u16* Wo_t  = (u16*)(ws + alloc(1048576UL * 2));
  u16* Qd    = (u16*)(ws + alloc(4194304UL * 2));
  u16* Kd    = (u16*)(ws + alloc(4194304UL * 2));
  u16* Vtd   = (u16*)(ws + alloc(4194304UL * 2));
  u16* ECd   = (u16*)(ws + alloc(33554432UL * 2));
  u16* EPd   = (u16*)(ws + alloc(33554432UL * 2));
  u16* ctx   = (u16*)(ws + alloc(4194304UL * 2));
  u16* idxt  = (u16*)(ws + alloc(2048UL * 2));
  float* qkvb = (float*)(ws + alloc(3072UL * 4));
  float* posb = (float*)(ws + alloc(2048UL * 4));
  // ---- dead-after-EC/EP-GEMM region (EB aliases from here) ----
  size_t dead0 = off;
  u16* h_bf  = (u16*)(ws + alloc(4194304UL * 2));
  u16* Wt5   = (u16*)(ws + alloc(5UL * 1048576 * 2));
  u16* re_bf = (u16*)(ws + alloc(524288UL * 2));
  u16* posk  = (u16*)(ws + alloc(524288UL * 2));
  u16* posq  = (u16*)(ws + alloc(524288UL * 2));
  u16* EB    = (u16*)(ws + dead0);
  const bool full = (ws_size >= dead0 + 134217728UL);
  (void)posq; (void)Kd;

  k_prep<<<6145, 256, 0, stream>>>(hs, Wq, Wk, Wv, Wpk, Wpq, Wo, rel, lng, lnb,
                                   bq, bk, bv, bpk, bpq,
                                   h_bf, Wt5, Wo_t, re_bf, idxt, qkvb, posb);

  k_gemm<5><<<dim3(24, 32, 1), 256, 0, stream>>>(h_bf, Wt5, qkvb, Qd, Vtd,
                                                 4096, 3072, 1024, 1024, 1024);
  k_gemm<3><<<dim3(8, 4, 2), 256, 0, stream>>>(re_bf, Wt5 + 3145728, posb, posk, nullptr,
                                               512, 1024, 1024, 1024, 1024);
  k_gemm<4><<<dim3(4, 8, 128), 256, 0, stream>>>(Qd, posk, nullptr, ECd, nullptr,
                                                 1024, 512, 64, 64, 64);

  if (full){
    k_bias   <<<dim3(2048), 256, 0, stream>>>(ECd, EPd, idxt, EB, 0);
    k_attn_eb<<<dim3(1024), 256, 0, stream>>>(Qd, Kd, Vtd, EB, ctx, 0);
  } else {
    k_bias   <<<dim3(1024), 256, 0, stream>>>(ECd, EPd, idxt, EB, 0);
    k_attn_eb<<<dim3(512),  256, 0, stream>>>(Qd, Kd, Vtd, EB, ctx, 0);
    k_bias   <<<dim3(1024), 256, 0, stream>>>(ECd, EPd, idxt, EB, 32);
    k_attn_eb<<<dim3(512),  256, 0, stream>>>(Qd, Kd, Vtd, EB, ctx, 32);
  }

  k_gemm<0><<<dim3(8, 32, 1), 256, 0, stream>>>(ctx, Wo_t, bo, d_out, nullptr,
                                                4096, 1024, 1024, 1024, 1024);
}

// Round 10
// 277.854 us; speedup vs baseline: 1.6347x; 1.0806x over previous
//
#include <hip/hip_runtime.h>

typedef unsigned short u16;
typedef __attribute__((ext_vector_type(8))) short short8_t;
typedef __attribute__((ext_vector_type(4))) float floatx4;

typedef const void __attribute__((address_space(1)))* gas_ptr;
typedef void __attribute__((address_space(3)))* las_ptr;

__device__ __forceinline__ float bf2f(u16 u){
  union { unsigned i; float f; } v; v.i = ((unsigned)u) << 16; return v.f;
}
__device__ __forceinline__ u16 f2bf(float x){
  unsigned u = __float_as_uint(x);
  return (u16)((u + 0x7FFFu + ((u >> 16) & 1u)) >> 16);
}
__device__ __forceinline__ int bucket_idx(int delta){
  int b;
  if (delta >= -128 && delta <= 128) b = delta;
  else {
    float a = (float)(delta < 0 ? -delta : delta);
    float lp = ceilf(logf(a * (1.0f / 128.0f)) / logf(511.0f / 128.0f) * 127.0f) + 128.0f;
    b = (int)lp;
    if (delta < 0) b = -b;
  }
  int idx = b + 256;
  return idx < 0 ? 0 : (idx > 511 ? 511 : idx);
}
__device__ __forceinline__ int win_lo(int s0, int t){
  int dlo = s0 - t * 64 - 63;
  int lo = bucket_idx(dlo) & ~1;
  return lo > 384 ? 384 : lo;
}

// ---------------- fused prep kernel ----------------
__global__ __launch_bounds__(256) void k_prep(
    const float* __restrict__ hs,
    const float* __restrict__ W0, const float* __restrict__ W1, const float* __restrict__ W2,
    const float* __restrict__ W3, const float* __restrict__ W4, const float* __restrict__ W5,
    const float* __restrict__ rel, const float* __restrict__ lng, const float* __restrict__ lnb,
    const float* __restrict__ bq, const float* __restrict__ bk, const float* __restrict__ bv,
    const float* __restrict__ bpk, const float* __restrict__ bpq,
    u16* __restrict__ h_bf, u16* __restrict__ Wt5, u16* __restrict__ Wo_t,
    u16* __restrict__ re_bf, u16* __restrict__ idxt,
    float* __restrict__ qkvb, float* __restrict__ posb)
{
  __shared__ float t[64][65];
  const int bid = blockIdx.x, tid = threadIdx.x;
  if (bid < 4096){
    int i = bid * 256 + tid;
    float4 v = ((const float4*)hs)[i];
    ushort4 o;
    o.x = f2bf(v.x); o.y = f2bf(v.y); o.z = f2bf(v.z); o.w = f2bf(v.w);
    ((ushort4*)h_bf)[i] = o;
  } else if (bid < 5632){
    int b2 = bid - 4096;
    int z = b2 >> 8, rem = b2 & 255;
    const float* W = (z == 0) ? W0 : (z == 1) ? W1 : (z == 2) ? W2 : (z == 3) ? W3 : (z == 4) ? W4 : W5;
    u16* Wt = (z < 5) ? (Wt5 + (long)z * 1048576) : Wo_t;
    int n0 = (rem & 15) * 64, k0 = (rem >> 4) * 64;
    #pragma unroll
    for (int i = 0; i < 16; i++){
      int e = i * 256 + tid; int r = e >> 6, c = e & 63;
      t[r][c] = W[(long)(k0 + r) * 1024 + n0 + c];
    }
    __syncthreads();
    #pragma unroll
    for (int i = 0; i < 16; i++){
      int e = i * 256 + tid; int r = e >> 6, c = e & 63;
      Wt[(long)(n0 + r) * 1024 + k0 + c] = f2bf(t[c][r]);
    }
  } else if (bid < 6144){
    int row = bid - 5632;
    float* red = (float*)t;
    float4 v = ((const float4*)(rel + (long)row * 1024))[tid];
    float s  = v.x + v.y + v.z + v.w;
    float s2 = v.x*v.x + v.y*v.y + v.z*v.z + v.w*v.w;
    #pragma unroll
    for (int o = 1; o < 64; o <<= 1){ s += __shfl_xor(s, o); s2 += __shfl_xor(s2, o); }
    if ((tid & 63) == 0){ red[(tid >> 6) * 2] = s; red[(tid >> 6) * 2 + 1] = s2; }
    __syncthreads();
    s  = red[0] + red[2] + red[4] + red[6];
    s2 = red[1] + red[3] + red[5] + red[7];
    float mu  = s * (1.f / 1024.f);
    float var = s2 * (1.f / 1024.f) - mu * mu;
    float rs  = rsqrtf(var + 1e-5f);
    float4 gg = ((const float4*)lng)[tid];
    float4 bb = ((const float4*)lnb)[tid];
    ushort4 o;
    o.x = f2bf((v.x - mu) * rs * gg.x + bb.x);
    o.y = f2bf((v.y - mu) * rs * gg.y + bb.y);
    o.z = f2bf((v.z - mu) * rs * gg.z + bb.z);
    o.w = f2bf((v.w - mu) * rs * gg.w + bb.w);
    ((ushort4*)(re_bf + (long)row * 1024))[tid] = o;
  } else {
    for (int i = tid; i < 2048; i += 256)
      idxt[i] = (u16)bucket_idx(i - 1024);
    for (int i = tid; i < 1024; i += 256){
      qkvb[i] = bq[i]; qkvb[1024 + i] = bk[i]; qkvb[2048 + i] = bv[i];
      posb[i] = bpk[i]; posb[1024 + i] = bpq[i];
    }
  }
}

// ---------------- MFMA GEMM ----------------
// MODE 0: f32 rowmajor (LDS-bounce coalesced float4)   MODE 3: pos GEMM z in {0,1}
// MODE 4: EC/EP batched z in [0,128): exp2(v*sB2), LDS-bounce coalesced
// MODE 5: fused QKV N=3072 (Q/K and V^T both LDS-bounce coalesced)
template<int MODE>
__global__ __launch_bounds__(256) void k_gemm(
    const u16* __restrict__ A, const u16* __restrict__ Bt,
    const float* __restrict__ bias, void* __restrict__ C, void* __restrict__ C2,
    int M, int N, int K, int lda, int ldb)
{
  __shared__ __attribute__((aligned(16))) u16 smem[16384];
  u16* As = smem;
  u16* Bs = smem + 8192;
  const int z = blockIdx.z;
  const u16* Ab = A;
  const u16* Bb = Bt;
  if (MODE == 3){ Bb = Bt + (long)z * 1048576; bias += z << 10; }
  if (MODE == 4){ Ab = A + (long)z * 65536; Bb = Bt + (long)(z >> 6) * 524288 + (long)(z & 15) * 32768; }
  const int m0 = blockIdx.y * 128, n0 = blockIdx.x * 128;
  const int tid = threadIdx.x, lane = tid & 63, w = tid >> 6;
  const int wm = (w >> 1) * 64, wn = (w & 1) * 64;
  floatx4 acc[4][4];
  #pragma unroll
  for (int i = 0; i < 4; i++)
    #pragma unroll
    for (int j = 0; j < 4; j++) acc[i][j] = (floatx4){0.f, 0.f, 0.f, 0.f};

  const int r8 = lane >> 3;
  const int cswz = ((lane & 7) ^ r8) << 4;

  for (int kt = 0; kt < K; kt += 64){
    #pragma unroll
    for (int c = 0; c < 4; c++){
      int row = (c * 4 + w) * 8 + r8;
      const char* ga = (const char*)(Ab + (long)(m0 + row) * lda + kt) + cswz;
      __builtin_amdgcn_global_load_lds((gas_ptr)ga, (las_ptr)((char*)As + (c * 4 + w) * 1024), 16, 0, 0);
      const char* gb = (const char*)(Bb + (long)(n0 + row) * ldb + kt) + cswz;
      __builtin_amdgcn_global_load_lds((gas_ptr)gb, (las_ptr)((char*)Bs + (c * 4 + w) * 1024), 16, 0, 0);
    }
    __syncthreads();
    short8_t af[2][4], bfr[2][4];
    #pragma unroll
    for (int kk = 0; kk < 2; kk++){
      #pragma unroll
      for (int i = 0; i < 4; i++){
        int ra = wm + i * 16 + (lane & 15);
        af[kk][i] = *(const short8_t*)((const char*)As + ra * 128 + ((kk * 64 + ((lane >> 4) << 4)) ^ ((ra & 7) << 4)));
        int rb = wn + i * 16 + (lane & 15);
        bfr[kk][i] = *(const short8_t*)((const char*)Bs + rb * 128 + ((kk * 64 + ((lane >> 4) << 4)) ^ ((rb & 7) << 4)));
      }
    }
    #pragma unroll
    for (int i = 0; i < 4; i++)
      #pragma unroll
      for (int j = 0; j < 4; j++){
        acc[i][j] = __builtin_amdgcn_mfma_f32_16x16x32_bf16(af[0][i], bfr[0][j], acc[i][j], 0, 0, 0);
        acc[i][j] = __builtin_amdgcn_mfma_f32_16x16x32_bf16(af[1][i], bfr[1][j], acc[i][j], 0, 0, 0);
      }
    __syncthreads();
  }

  if (MODE == 0){
    // f32 out via LDS bounce, two 128x64 halves (32 KB each)
    float* fs = (float*)smem;
    #pragma unroll
    for (int h = 0; h < 2; h++){
      if ((w & 1) == h){
        #pragma unroll
        for (int i = 0; i < 4; i++)
          #pragma unroll
          for (int j = 0; j < 4; j++)
            #pragma unroll
            for (int r = 0; r < 4; r++){
              int ml = wm + i * 16 + ((lane >> 4) << 2) + r;
              int nl = j * 16 + (lane & 15);
              fs[ml * 64 + (nl ^ (((ml >> 2) & 3) << 4))] = acc[i][j][r] + bias[n0 + h * 64 + nl];
            }
      }
      __syncthreads();
      const int row16 = tid >> 4, cch = tid & 15;
      #pragma unroll
      for (int rr = 0; rr < 8; rr++){
        int ml = rr * 16 + row16;
        float4 vv = *(const float4*)&fs[ml * 64 + ((cch * 4) ^ (((ml >> 2) & 3) << 4))];
        *(float4*)((float*)C + (long)(m0 + ml) * N + n0 + h * 64 + cch * 4) = vv;
      }
      __syncthreads();
    }
    return;
  }

  if (MODE == 4){
    // exp2 + bf16 into LDS (swizzled), then coalesced short8 row stores
    #pragma unroll
    for (int i = 0; i < 4; i++){
      #pragma unroll
      for (int j = 0; j < 4; j++){
        #pragma unroll
        for (int r = 0; r < 4; r++){
          int ml = wm + i * 16 + ((lane >> 4) << 2) + r;
          int nl = wn + j * 16 + (lane & 15);
          int byte_ = ml * 256 + ((nl * 2) ^ ((ml & 7) << 4));
          *(u16*)((char*)smem + byte_) = f2bf(exp2f(acc[i][j][r] * 0.12751743f));
        }
      }
    }
    __syncthreads();
    const int row16 = tid >> 4, cch = tid & 15;
    #pragma unroll
    for (int rr = 0; rr < 8; rr++){
      int ml = rr * 16 + row16;
      short8_t vv = *(const short8_t*)((const char*)smem + ml * 256 + ((cch * 16) ^ ((ml & 7) << 4)));
      *(short8_t*)((u16*)C + (long)z * 524288 + (long)(m0 + ml) * 512 + n0 + cch * 8) = vv;
    }
    return;
  }

  if (MODE == 5){
    if (n0 >= 2048){
      // V^T via LDS-bounce (transposed tile), coalesced along s
      #pragma unroll
      for (int i = 0; i < 4; i++){
        #pragma unroll
        for (int j = 0; j < 4; j++){
          #pragma unroll
          for (int r = 0; r < 4; r++){
            int ml = wm + i * 16 + ((lane >> 4) << 2) + r;
            int nl = wn + j * 16 + (lane & 15);
            float v = acc[i][j][r] + bias[n0 + nl];
            int byte_ = nl * 256 + ((ml * 2) ^ ((nl & 7) << 4));
            *(u16*)((char*)smem + byte_) = f2bf(v);
          }
        }
      }
      __syncthreads();
      #pragma unroll
      for (int rr = 0; rr < 8; rr++){
        int nl = rr * 16 + (tid >> 4);
        int np = n0 + nl - 2048;
        int mc = tid & 15;
        short8_t vv = *(const short8_t*)((const char*)smem + nl * 256 + ((mc * 16) ^ ((nl & 7) << 4)));
        int m = m0 + mc * 8;
        long base = ((long)((m >> 10) * 16 + (np >> 6)) * 64 + (np & 63)) * 1024 + (m & 1023);
        *(short8_t*)((u16*)C2 + base) = vv;
      }
    } else {
      // Q/K via LDS-bounce (row-major tile), coalesced along d within head
      #pragma unroll
      for (int i = 0; i < 4; i++){
        #pragma unroll
        for (int j = 0; j < 4; j++){
          #pragma unroll
          for (int r = 0; r < 4; r++){
            int ml = wm + i * 16 + ((lane >> 4) << 2) + r;
            int nl = wn + j * 16 + (lane & 15);
            float v = acc[i][j][r] + bias[n0 + nl];
            int byte_ = ml * 256 + ((nl * 2) ^ ((ml & 7) << 4));
            *(u16*)((char*)smem + byte_) = f2bf(v);
          }
        }
      }
      __syncthreads();
      const int row16 = tid >> 4, cch = tid & 15;
      const int mat = n0 >> 10;
      u16* Cd = (u16*)C + (long)mat * 4194304;
      #pragma unroll
      for (int rr = 0; rr < 8; rr++){
        int ml = rr * 16 + row16;
        short8_t vv = *(const short8_t*)((const char*)smem + ml * 256 + ((cch * 16) ^ ((ml & 7) << 4)));
        int m = m0 + ml;
        int np = (n0 & 1023) + cch * 8;
        long base = ((long)((m >> 10) * 16 + (np >> 6)) * 1024 + (m & 1023)) * 64 + (np & 63);
        *(short8_t*)(Cd + base) = vv;
      }
    }
    return;
  }

  // MODE 3 (small): scalar epilogue
  #pragma unroll
  for (int i = 0; i < 4; i++){
    #pragma unroll
    for (int j = 0; j < 4; j++){
      #pragma unroll
      for (int r = 0; r < 4; r++){
        int m = m0 + wm + i * 16 + ((lane >> 4) << 2) + r;
        int n = n0 + wn + j * 16 + (lane & 15);
        float v = acc[i][j][r] + bias[n];
        ((u16*)C)[(long)z * 524288 + ((long)(n >> 6) * 512 + m) * 64 + (n & 63)] = f2bf(v);
      }
    }
  }
}

// ---------------- k_bias: EB[bhl][s][k] = EC[s][ix] * EP[k][ix] ----------------
__global__ __launch_bounds__(256, 2) void k_bias(
    const u16* __restrict__ EC, const u16* __restrict__ EP,
    const u16* __restrict__ T3, u16* __restrict__ EB, int bhbase)
{
  __shared__ __attribute__((aligned(16))) u16 C2W[2][8192];
  __shared__ __attribute__((aligned(16))) u16 P2W[2][8192];
  __shared__ __attribute__((aligned(16))) u16 IDW[2][128];
  const int flat0 = blockIdx.x;
  const int chunk = gridDim.x >> 3;
  const int flat = (flat0 & 7) * chunk + (flat0 >> 3);
  const int bhl = flat >> 5;
  const int sb  = (flat >> 1) & 15;
  const int kq  = flat & 1;
  const int bh = bhbase + bhl;
  const int tid = threadIdx.x, lane = tid & 63, w = tid >> 6;
  const int s0 = sb * 64;
  const u16* c2b = EC + (long)bh * 524288;
  const u16* p2b = EP + (long)bh * 524288;
  u16* EBb = EB + ((long)bhl << 20);

  const int r2 = tid >> 2;
  const int q2 = tid & 3;
  const int c2key = (r2 & 15) << 4;

  auto STAGE = [&](int buf, int t){
    const int ixlo = win_lo(s0, t);
    const int k0 = t * 64;
    #pragma unroll
    for (int r = 0; r < 16; r++){
      int row = w * 16 + r;
      const char* sa = (const char*)(c2b + (long)(s0 + row) * 512 + ixlo) + ((lane * 4) ^ ((row & 15) << 4));
      __builtin_amdgcn_global_load_lds((gas_ptr)sa, (las_ptr)((char*)&C2W[buf][0] + row * 256), 4, 0, 0);
      const char* sp = (const char*)(p2b + (long)(k0 + row) * 512 + ixlo) + ((lane * 4) ^ ((row & 15) << 4));
      __builtin_amdgcn_global_load_lds((gas_ptr)sp, (las_ptr)((char*)&P2W[buf][0] + row * 256), 4, 0, 0);
    }
    if (w == 3){
      int dev = s0 - k0 - 64;
      __builtin_amdgcn_global_load_lds((gas_ptr)((const char*)(T3 + (dev + 1024)) + lane * 4),
                                       (las_ptr)((char*)&IDW[buf][0]), 4, 0, 0);
    }
  };

  const int t0 = kq * 8;
  STAGE(0, t0);
  asm volatile("s_waitcnt vmcnt(0)" ::: "memory");
  __builtin_amdgcn_s_barrier();

  for (int i = 0; i < 8; i++){
    const int t = t0 + i, buf = i & 1;
    const int k0 = t * 64;
    const int ixlo = win_lo(s0, t);

    if (i < 7) STAGE(buf ^ 1, t + 1);

    u16 ov[16];
    #pragma unroll
    for (int c = 0; c < 16; c++){
      int kl = q2 * 16 + c;
      int j = r2 - kl + 64;
      int ix = (int)IDW[buf][j];
      int x = (ix - ixlo) * 2;
      float b1 = bf2f(*(const u16*)((const char*)&C2W[buf][0] + r2 * 256 + (x ^ c2key)));
      float b2 = bf2f(*(const u16*)((const char*)&P2W[buf][0] + kl * 256 + (x ^ ((kl & 15) << 4))));
      ov[c] = f2bf(b1 * b2);
    }
    u16* dst = EBb + (((long)(s0 + r2)) << 10) + k0 + q2 * 16;
    uint4 st0, st1;
    st0.x = (unsigned)ov[0]  | ((unsigned)ov[1]  << 16);
    st0.y = (unsigned)ov[2]  | ((unsigned)ov[3]  << 16);
    st0.z = (unsigned)ov[4]  | ((unsigned)ov[5]  << 16);
    st0.w = (unsigned)ov[6]  | ((unsigned)ov[7]  << 16);
    st1.x = (unsigned)ov[8]  | ((unsigned)ov[9]  << 16);
    st1.y = (unsigned)ov[10] | ((unsigned)ov[11] << 16);
    st1.z = (unsigned)ov[12] | ((unsigned)ov[13] << 16);
    st1.w = (unsigned)ov[14] | ((unsigned)ov[15] << 16);
    *(uint4*)dst = st0;
    *(uint4*)(dst + 8) = st1;

    if (i < 7){
      asm volatile("s_waitcnt vmcnt(2)" ::: "memory");
      __builtin_amdgcn_s_barrier();
    }
  }
}

// ---------------- k_attn_eb: streaming flash attn, bias pre-exp'd ----------------
__global__ __launch_bounds__(256, 3) void k_attn_eb(
    const u16* __restrict__ Q, const u16* __restrict__ K, const u16* __restrict__ Vt,
    const u16* __restrict__ EB, u16* __restrict__ ctx, int bhbase)
{
  __shared__ __attribute__((aligned(16))) u16 Ks[2][4096];
  __shared__ __attribute__((aligned(16))) u16 Vs[2][4096];
  __shared__ __attribute__((aligned(16))) u16 EBs[4096];
  __shared__ __attribute__((aligned(16))) u16 Pt[4096];
  const int flat0 = blockIdx.x;
  const int chunk = gridDim.x >> 3;
  const int flat = (flat0 & 7) * chunk + (flat0 >> 3);
  const int bhl = flat >> 4, sb = flat & 15;
  const int bh = bhbase + bhl;
  const int tid = threadIdx.x, lane = tid & 63, w = tid >> 6;
  const int s15 = lane & 15, g = lane >> 4;
  const int s0 = sb * 64;
  const int myrow = w * 16 + s15;
  const int s_row = s0 + myrow;
  const u16* Qb  = Q   + (long)bh * 65536;
  const u16* Kg  = K   + (long)bh * 65536;
  const u16* Vg  = Vt  + (long)bh * 65536;
  const u16* EBg = EB  + ((long)bhl << 20);

  short8_t qf0 = *(const short8_t*)(Qb + (long)s_row * 64 + g * 8);
  short8_t qf1 = *(const short8_t*)(Qb + (long)s_row * 64 + 32 + g * 8);

  const int srow8  = lane >> 3;
  const int schunk = (lane & 7) ^ srow8;
  const float sA2 = 0.10411754f;   // log2(e)/sqrt(192)

  auto STAGE_KV = [&](int buf, int kt){
    #pragma unroll
    for (int ii = 0; ii < 2; ii++){
      int i = w * 2 + ii;
      int row = i * 8 + srow8;
      __builtin_amdgcn_global_load_lds(
        (gas_ptr)((const char*)(Kg + (long)(kt + row) * 64) + schunk * 16),
        (las_ptr)((char*)&Ks[buf][0] + i * 1024), 16, 0, 0);
      __builtin_amdgcn_global_load_lds(
        (gas_ptr)((const char*)(Vg + (long)row * 1024 + kt) + schunk * 16),
        (las_ptr)((char*)&Vs[buf][0] + i * 1024), 16, 0, 0);
    }
  };
  auto STAGE_EB = [&](int kt){
    #pragma unroll
    for (int ii = 0; ii < 2; ii++){
      int rowl = w * 16 + ii * 8 + srow8;
      const char* src = (const char*)(EBg + (((long)(s0 + rowl)) << 10) + kt) + schunk * 16;
      __builtin_amdgcn_global_load_lds((gas_ptr)src,
        (las_ptr)((char*)EBs + (w * 2 + ii) * 1024), 16, 0, 0);
    }
  };

  STAGE_KV(0, 0);
  STAGE_EB(0);

  float rowsum = 0.f;
  floatx4 oacc[4];
  #pragma unroll
  for (int dt = 0; dt < 4; dt++) oacc[dt] = (floatx4){0.f, 0.f, 0.f, 0.f};

  const int psw = (myrow & 7) << 4;

  for (int t = 0; t < 16; t++){
    const int buf = t & 1;
    const int kt = t * 64;

    asm volatile("s_waitcnt vmcnt(2)" ::: "memory");
    asm volatile("s_waitcnt lgkmcnt(0)" ::: "memory");
    __builtin_amdgcn_s_barrier();

    STAGE_KV(buf ^ 1, (t < 15) ? kt + 64 : 0);

    floatx4 a[4];
    #pragma unroll
    for (int T = 0; T < 4; T++){
      int row = T * 16 + s15;
      const char* rp = (const char*)&Ks[buf][0] + row * 128;
      int sw = (row & 7) << 4;
      short8_t k0v = *(const short8_t*)(rp + ((g * 16) ^ sw));
      short8_t k1v = *(const short8_t*)(rp + ((64 + g * 16) ^ sw));
      floatx4 acc = (floatx4){0.f, 0.f, 0.f, 0.f};
      acc = __builtin_amdgcn_mfma_f32_16x16x32_bf16(k0v, qf0, acc, 0, 0, 0);
      acc = __builtin_amdgcn_mfma_f32_16x16x32_bf16(k1v, qf1, acc, 0, 0, 0);
      a[T] = acc;
    }

    asm volatile("s_waitcnt vmcnt(4)" ::: "memory");

    #pragma unroll
    for (int T = 0; T < 4; T++){
      uint2 ebv = *(const uint2*)((const char*)EBs + myrow * 128 + ((T * 32 + g * 8) ^ psw));
      float e0 = exp2f(a[T][0] * sA2) * bf2f((u16)(ebv.x & 0xffff));
      float e1 = exp2f(a[T][1] * sA2) * bf2f((u16)(ebv.x >> 16));
      float e2 = exp2f(a[T][2] * sA2) * bf2f((u16)(ebv.y & 0xffff));
      float e3 = exp2f(a[T][3] * sA2) * bf2f((u16)(ebv.y >> 16));
      u16 p0 = f2bf(e0), p1 = f2bf(e1), p2v = f2bf(e2), p3 = f2bf(e3);
      rowsum += (bf2f(p0) + bf2f(p1)) + (bf2f(p2v) + bf2f(p3));
      uint2 pk2;
      pk2.x = (unsigned)p0  | ((unsigned)p1 << 16);
      pk2.y = (unsigned)p2v | ((unsigned)p3 << 16);
      *(uint2*)((char*)Pt + myrow * 128 + ((T * 32 + g * 8) ^ psw)) = pk2;
    }

    asm volatile("s_waitcnt lgkmcnt(0)" ::: "memory");
    STAGE_EB((t < 15) ? kt + 64 : 0);

    #pragma unroll
    for (int M = 0; M < 2; M++){
      short8_t pf = *(const short8_t*)((const char*)Pt + myrow * 128 + ((M * 64 + g * 16) ^ psw));
      #pragma unroll
      for (int dt = 0; dt < 4; dt++){
        int drow = dt * 16 + s15;
        short8_t vf = *(const short8_t*)((const char*)&Vs[buf][0] + drow * 128 + ((M * 64 + g * 16) ^ ((drow & 7) << 4)));
        oacc[dt] = __builtin_amdgcn_mfma_f32_16x16x32_bf16(pf, vf, oacc[dt], 0, 0, 0);
      }
    }
  }

  asm volatile("s_waitcnt vmcnt(0)" ::: "memory");

  rowsum += __shfl_xor(rowsum, 16);
  rowsum += __shfl_xor(rowsum, 32);
  float rinv = 1.f / rowsum;

  const int b = bh >> 4, h = bh & 15;
  #pragma unroll
  for (int r = 0; r < 4; r++){
    float ri = __shfl(rinv, g * 4 + r);
    int s_out = s0 + w * 16 + g * 4 + r;
    #pragma unroll
    for (int dt = 0; dt < 4; dt++){
      long oi = ((long)b * 1024 + s_out) * 1024 + h * 64 + dt * 16 + s15;
      ctx[oi] = f2bf(oacc[dt][r] * ri);
    }
  }
}

// ---------------- launch ----------------
extern "C" void kernel_launch(void* const* d_in, const int* in_sizes, int n_in,
                              void* d_out, int out_size, void* d_ws, size_t ws_size,
                              hipStream_t stream){
  const float* hs  = (const float*)d_in[0];
  const float* Wq  = (const float*)d_in[1];
  const float* bq  = (const float*)d_in[2];
  const float* Wk  = (const float*)d_in[3];
  const float* bk  = (const float*)d_in[4];
  const float* Wv  = (const float*)d_in[5];
  const float* bv  = (const float*)d_in[6];
  const float* Wo  = (const float*)d_in[7];
  const float* bo  = (const float*)d_in[8];
  const float* rel = (const float*)d_in[9];
  const float* lng = (const float*)d_in[10];
  const float* lnb = (const float*)d_in[11];
  const float* Wpk = (const float*)d_in[12];
  const float* bpk = (const float*)d_in[13];
  const float* Wpq = (const float*)d_in[14];
  const float* bpq = (const float*)d_in[15];

  char* ws = (char*)d_ws;
  size_t off = 0;
  auto alloc = [&](size_t bytes){ size_t o = off; off += (bytes + 255) & ~(size_t)255; return o; };
  // ---- live-through-end region ----
  u16* Wo_t  = (u16*)(ws + alloc(1048576UL * 2));
  u16* Qd    = (u16*)(ws + alloc(4194304UL * 2));
  u16* Kd    = (u16*)(ws + alloc(4194304UL * 2));
  u16* Vtd   = (u16*)(ws + alloc(4194304UL * 2));
  u16* ECd   = (u16*)(ws + alloc(33554432UL * 2));
  u16* EPd   = (u16*)(ws + alloc(33554432UL * 2));
  u16* ctx   = (u16*)(ws + alloc(4194304UL * 2));
  u16* idxt  = (u16*)(ws + alloc(2048UL * 2));
  float* qkvb = (float*)(ws + alloc(3072UL * 4));
  float* posb = (float*)(ws + alloc(2048UL * 4));
  // ---- dead-after-EC/EP-GEMM region (EB aliases from here) ----
  size_t dead0 = off;
  u16* h_bf  = (u16*)(ws + alloc(4194304UL * 2));
  u16* Wt5   = (u16*)(ws + alloc(5UL * 1048576 * 2));
  u16* re_bf = (u16*)(ws + alloc(524288UL * 2));
  u16* posk  = (u16*)(ws + alloc(524288UL * 2));
  u16* posq  = (u16*)(ws + alloc(524288UL * 2));
  u16* EB    = (u16*)(ws + dead0);
  const bool full = (ws_size >= dead0 + 134217728UL);
  (void)posq; (void)Kd;

  k_prep<<<6145, 256, 0, stream>>>(hs, Wq, Wk, Wv, Wpk, Wpq, Wo, rel, lng, lnb,
                                   bq, bk, bv, bpk, bpq,
                                   h_bf, Wt5, Wo_t, re_bf, idxt, qkvb, posb);

  k_gemm<5><<<dim3(24, 32, 1), 256, 0, stream>>>(h_bf, Wt5, qkvb, Qd, Vtd,
                                                 4096, 3072, 1024, 1024, 1024);
  k_gemm<3><<<dim3(8, 4, 2), 256, 0, stream>>>(re_bf, Wt5 + 3145728, posb, posk, nullptr,
                                               512, 1024, 1024, 1024, 1024);
  k_gemm<4><<<dim3(4, 8, 128), 256, 0, stream>>>(Qd, posk, nullptr, ECd, nullptr,
                                                 1024, 512, 64, 64, 64);

  if (full){
    k_bias   <<<dim3(2048), 256, 0, stream>>>(ECd, EPd, idxt, EB, 0);
    k_attn_eb<<<dim3(1024), 256, 0, stream>>>(Qd, Kd, Vtd, EB, ctx, 0);
  } else {
    k_bias   <<<dim3(1024), 256, 0, stream>>>(ECd, EPd, idxt, EB, 0);
    k_attn_eb<<<dim3(512),  256, 0, stream>>>(Qd, Kd, Vtd, EB, ctx, 0);
    k_bias   <<<dim3(1024), 256, 0, stream>>>(ECd, EPd, idxt, EB, 32);
    k_attn_eb<<<dim3(512),  256, 0, stream>>>(Qd, Kd, Vtd, EB, ctx, 32);
  }

  k_gemm<0><<<dim3(8, 32, 1), 256, 0, stream>>>(ctx, Wo_t, bo, d_out, nullptr,
                                                4096, 1024, 1024, 1024, 1024);
}

// Round 11
// 258.767 us; speedup vs baseline: 1.7553x; 1.0738x over previous
//
#include <hip/hip_runtime.h>

typedef unsigned short u16;
typedef __attribute__((ext_vector_type(8))) short short8_t;
typedef __attribute__((ext_vector_type(4))) float floatx4;

typedef const void __attribute__((address_space(1)))* gas_ptr;
typedef void __attribute__((address_space(3)))* las_ptr;

__device__ __forceinline__ float bf2f(u16 u){
  union { unsigned i; float f; } v; v.i = ((unsigned)u) << 16; return v.f;
}
__device__ __forceinline__ u16 f2bf(float x){
  unsigned u = __float_as_uint(x);
  return (u16)((u + 0x7FFFu + ((u >> 16) & 1u)) >> 16);
}
__device__ __forceinline__ int bucket_idx(int delta){
  int b;
  if (delta >= -128 && delta <= 128) b = delta;
  else {
    float a = (float)(delta < 0 ? -delta : delta);
    float lp = ceilf(logf(a * (1.0f / 128.0f)) / logf(511.0f / 128.0f) * 127.0f) + 128.0f;
    b = (int)lp;
    if (delta < 0) b = -b;
  }
  int idx = b + 256;
  return idx < 0 ? 0 : (idx > 511 ? 511 : idx);
}
__device__ __forceinline__ int win_lo(int s0, int t){
  int dlo = s0 - t * 64 - 63;
  int lo = bucket_idx(dlo) & ~1;
  return lo > 384 ? 384 : lo;
}

// ---------------- fused prep kernel ----------------
__global__ __launch_bounds__(256) void k_prep(
    const float* __restrict__ hs,
    const float* __restrict__ W0, const float* __restrict__ W1, const float* __restrict__ W2,
    const float* __restrict__ W3, const float* __restrict__ W4, const float* __restrict__ W5,
    const float* __restrict__ rel, const float* __restrict__ lng, const float* __restrict__ lnb,
    const float* __restrict__ bq, const float* __restrict__ bk, const float* __restrict__ bv,
    const float* __restrict__ bpk, const float* __restrict__ bpq,
    u16* __restrict__ h_bf, u16* __restrict__ Wt5, u16* __restrict__ Wo_t,
    u16* __restrict__ re_bf, u16* __restrict__ idxt,
    float* __restrict__ qkvb, float* __restrict__ posb)
{
  __shared__ float t[64][65];
  const int bid = blockIdx.x, tid = threadIdx.x;
  if (bid < 4096){
    int i = bid * 256 + tid;
    float4 v = ((const float4*)hs)[i];
    ushort4 o;
    o.x = f2bf(v.x); o.y = f2bf(v.y); o.z = f2bf(v.z); o.w = f2bf(v.w);
    ((ushort4*)h_bf)[i] = o;
  } else if (bid < 5632){
    int b2 = bid - 4096;
    int z = b2 >> 8, rem = b2 & 255;
    const float* W = (z == 0) ? W0 : (z == 1) ? W1 : (z == 2) ? W2 : (z == 3) ? W3 : (z == 4) ? W4 : W5;
    u16* Wt = (z < 5) ? (Wt5 + (long)z * 1048576) : Wo_t;
    int n0 = (rem & 15) * 64, k0 = (rem >> 4) * 64;
    #pragma unroll
    for (int i = 0; i < 16; i++){
      int e = i * 256 + tid; int r = e >> 6, c = e & 63;
      t[r][c] = W[(long)(k0 + r) * 1024 + n0 + c];
    }
    __syncthreads();
    #pragma unroll
    for (int i = 0; i < 16; i++){
      int e = i * 256 + tid; int r = e >> 6, c = e & 63;
      Wt[(long)(n0 + r) * 1024 + k0 + c] = f2bf(t[c][r]);
    }
  } else if (bid < 6144){
    int row = bid - 5632;
    float* red = (float*)t;
    float4 v = ((const float4*)(rel + (long)row * 1024))[tid];
    float s  = v.x + v.y + v.z + v.w;
    float s2 = v.x*v.x + v.y*v.y + v.z*v.z + v.w*v.w;
    #pragma unroll
    for (int o = 1; o < 64; o <<= 1){ s += __shfl_xor(s, o); s2 += __shfl_xor(s2, o); }
    if ((tid & 63) == 0){ red[(tid >> 6) * 2] = s; red[(tid >> 6) * 2 + 1] = s2; }
    __syncthreads();
    s  = red[0] + red[2] + red[4] + red[6];
    s2 = red[1] + red[3] + red[5] + red[7];
    float mu  = s * (1.f / 1024.f);
    float var = s2 * (1.f / 1024.f) - mu * mu;
    float rs  = rsqrtf(var + 1e-5f);
    float4 gg = ((const float4*)lng)[tid];
    float4 bb = ((const float4*)lnb)[tid];
    ushort4 o;
    o.x = f2bf((v.x - mu) * rs * gg.x + bb.x);
    o.y = f2bf((v.y - mu) * rs * gg.y + bb.y);
    o.z = f2bf((v.z - mu) * rs * gg.z + bb.z);
    o.w = f2bf((v.w - mu) * rs * gg.w + bb.w);
    ((ushort4*)(re_bf + (long)row * 1024))[tid] = o;
  } else {
    for (int i = tid; i < 2048; i += 256)
      idxt[i] = (u16)bucket_idx(i - 1024);
    for (int i = tid; i < 1024; i += 256){
      qkvb[i] = bq[i]; qkvb[1024 + i] = bk[i]; qkvb[2048 + i] = bv[i];
      posb[i] = bpk[i]; posb[1024 + i] = bpq[i];
    }
  }
}

// ---------------- MFMA GEMM ----------------
// MODE 0: f32 rowmajor (LDS-bounce, XCD-swizzled grid)
// MODE 4: EC/EP batched z in [0,128): exp2(v*sB2), LDS-bounce coalesced
// MODE 5: fused QKV N=3072 (XCD-swizzled) + pos GEMM folded in at by>=32
template<int MODE>
__global__ __launch_bounds__(256) void k_gemm(
    const u16* __restrict__ A, const u16* __restrict__ Bt,
    const float* __restrict__ bias, void* __restrict__ C, void* __restrict__ C2,
    int M, int N, int K, int lda, int ldb,
    const u16* __restrict__ Apos, const float* __restrict__ biaspos, void* __restrict__ Cpos)
{
  __shared__ __attribute__((aligned(16))) u16 smem[16384];
  u16* As = smem;
  u16* Bs = smem + 8192;
  const int bx = blockIdx.x, by = blockIdx.y;
  const int z = blockIdx.z;
  const u16* Ab = A;
  const u16* Bb = Bt;
  const float* biasv = bias;
  bool pospath = false;
  int pz = 0;
  int m0, n0;
  if (MODE == 5){
    if (by >= 32){
      if (bx >= 16) return;
      pospath = true;
      pz = bx >> 3;
      Ab = Apos;
      Bb = Bt + 3145728 + (long)pz * 1048576;
      biasv = biaspos + (pz << 10);
      m0 = (by - 32) * 128;
      n0 = (bx & 7) * 128;
    } else {
      // XCD-bijective chunking: 768 = 8 x 96; each XCD owns 4 contiguous m-panels
      int bid = by * 24 + bx;
      int nf = (bid & 7) * 96 + (bid >> 3);
      m0 = (nf / 24) * 128;
      n0 = (nf % 24) * 128;
    }
  } else if (MODE == 0){
    // 256 = 8 x 32; each XCD owns 4 contiguous m-panels
    int bid = by * 8 + bx;
    int nf = (bid & 7) * 32 + (bid >> 3);
    m0 = (nf >> 3) * 128;
    n0 = (nf & 7) * 128;
  } else {
    if (MODE == 4){ Ab = A + (long)z * 65536; Bb = Bt + (long)(z >> 6) * 524288 + (long)(z & 15) * 32768; }
    m0 = by * 128;
    n0 = bx * 128;
  }
  const int tid = threadIdx.x, lane = tid & 63, w = tid >> 6;
  const int wm = (w >> 1) * 64, wn = (w & 1) * 64;
  floatx4 acc[4][4];
  #pragma unroll
  for (int i = 0; i < 4; i++)
    #pragma unroll
    for (int j = 0; j < 4; j++) acc[i][j] = (floatx4){0.f, 0.f, 0.f, 0.f};

  const int r8 = lane >> 3;
  const int cswz = ((lane & 7) ^ r8) << 4;

  for (int kt = 0; kt < K; kt += 64){
    #pragma unroll
    for (int c = 0; c < 4; c++){
      int row = (c * 4 + w) * 8 + r8;
      const char* ga = (const char*)(Ab + (long)(m0 + row) * lda + kt) + cswz;
      __builtin_amdgcn_global_load_lds((gas_ptr)ga, (las_ptr)((char*)As + (c * 4 + w) * 1024), 16, 0, 0);
      const char* gb = (const char*)(Bb + (long)(n0 + row) * ldb + kt) + cswz;
      __builtin_amdgcn_global_load_lds((gas_ptr)gb, (las_ptr)((char*)Bs + (c * 4 + w) * 1024), 16, 0, 0);
    }
    __syncthreads();
    short8_t af[2][4], bfr[2][4];
    #pragma unroll
    for (int kk = 0; kk < 2; kk++){
      #pragma unroll
      for (int i = 0; i < 4; i++){
        int ra = wm + i * 16 + (lane & 15);
        af[kk][i] = *(const short8_t*)((const char*)As + ra * 128 + ((kk * 64 + ((lane >> 4) << 4)) ^ ((ra & 7) << 4)));
        int rb = wn + i * 16 + (lane & 15);
        bfr[kk][i] = *(const short8_t*)((const char*)Bs + rb * 128 + ((kk * 64 + ((lane >> 4) << 4)) ^ ((rb & 7) << 4)));
      }
    }
    #pragma unroll
    for (int i = 0; i < 4; i++)
      #pragma unroll
      for (int j = 0; j < 4; j++){
        acc[i][j] = __builtin_amdgcn_mfma_f32_16x16x32_bf16(af[0][i], bfr[0][j], acc[i][j], 0, 0, 0);
        acc[i][j] = __builtin_amdgcn_mfma_f32_16x16x32_bf16(af[1][i], bfr[1][j], acc[i][j], 0, 0, 0);
      }
    __syncthreads();
  }

  if (MODE == 0){
    // f32 out via LDS bounce, two 128x64 halves
    float* fs = (float*)smem;
    #pragma unroll
    for (int h = 0; h < 2; h++){
      if ((w & 1) == h){
        #pragma unroll
        for (int i = 0; i < 4; i++)
          #pragma unroll
          for (int j = 0; j < 4; j++)
            #pragma unroll
            for (int r = 0; r < 4; r++){
              int ml = wm + i * 16 + ((lane >> 4) << 2) + r;
              int nl = j * 16 + (lane & 15);
              fs[ml * 64 + (nl ^ (((ml >> 2) & 3) << 4))] = acc[i][j][r] + biasv[n0 + h * 64 + nl];
            }
      }
      __syncthreads();
      const int row16 = tid >> 4, cch = tid & 15;
      #pragma unroll
      for (int rr = 0; rr < 8; rr++){
        int ml = rr * 16 + row16;
        float4 vv = *(const float4*)&fs[ml * 64 + ((cch * 4) ^ (((ml >> 2) & 3) << 4))];
        *(float4*)((float*)C + (long)(m0 + ml) * N + n0 + h * 64 + cch * 4) = vv;
      }
      __syncthreads();
    }
    return;
  }

  if (MODE == 4){
    // exp2 + bf16 into LDS (swizzled), then coalesced short8 row stores
    #pragma unroll
    for (int i = 0; i < 4; i++){
      #pragma unroll
      for (int j = 0; j < 4; j++){
        #pragma unroll
        for (int r = 0; r < 4; r++){
          int ml = wm + i * 16 + ((lane >> 4) << 2) + r;
          int nl = wn + j * 16 + (lane & 15);
          int byte_ = ml * 256 + ((nl * 2) ^ ((ml & 7) << 4));
          *(u16*)((char*)smem + byte_) = f2bf(exp2f(acc[i][j][r] * 0.12751743f));
        }
      }
    }
    __syncthreads();
    const int row16 = tid >> 4, cch = tid & 15;
    #pragma unroll
    for (int rr = 0; rr < 8; rr++){
      int ml = rr * 16 + row16;
      short8_t vv = *(const short8_t*)((const char*)smem + ml * 256 + ((cch * 16) ^ ((ml & 7) << 4)));
      *(short8_t*)((u16*)C + (long)z * 524288 + (long)(m0 + ml) * 512 + n0 + cch * 8) = vv;
    }
    return;
  }

  if (MODE == 5){
    if (pospath){
      // pos GEMM epilogue: [pz][h][512][64], scalar (tiny: 64 blocks)
      #pragma unroll
      for (int i = 0; i < 4; i++){
        #pragma unroll
        for (int j = 0; j < 4; j++){
          #pragma unroll
          for (int r = 0; r < 4; r++){
            int m = m0 + wm + i * 16 + ((lane >> 4) << 2) + r;
            int n = n0 + wn + j * 16 + (lane & 15);
            float v = acc[i][j][r] + biasv[n];
            ((u16*)Cpos)[(long)pz * 524288 + ((long)(n >> 6) * 512 + m) * 64 + (n & 63)] = f2bf(v);
          }
        }
      }
      return;
    }
    if (n0 >= 2048){
      // V^T via LDS-bounce (transposed tile), coalesced along s
      #pragma unroll
      for (int i = 0; i < 4; i++){
        #pragma unroll
        for (int j = 0; j < 4; j++){
          #pragma unroll
          for (int r = 0; r < 4; r++){
            int ml = wm + i * 16 + ((lane >> 4) << 2) + r;
            int nl = wn + j * 16 + (lane & 15);
            float v = acc[i][j][r] + biasv[n0 + nl];
            int byte_ = nl * 256 + ((ml * 2) ^ ((nl & 7) << 4));
            *(u16*)((char*)smem + byte_) = f2bf(v);
          }
        }
      }
      __syncthreads();
      #pragma unroll
      for (int rr = 0; rr < 8; rr++){
        int nl = rr * 16 + (tid >> 4);
        int np = n0 + nl - 2048;
        int mc = tid & 15;
        short8_t vv = *(const short8_t*)((const char*)smem + nl * 256 + ((mc * 16) ^ ((nl & 7) << 4)));
        int m = m0 + mc * 8;
        long base = ((long)((m >> 10) * 16 + (np >> 6)) * 64 + (np & 63)) * 1024 + (m & 1023);
        *(short8_t*)((u16*)C2 + base) = vv;
      }
    } else {
      // Q/K via LDS-bounce (row-major tile), coalesced along d within head
      #pragma unroll
      for (int i = 0; i < 4; i++){
        #pragma unroll
        for (int j = 0; j < 4; j++){
          #pragma unroll
          for (int r = 0; r < 4; r++){
            int ml = wm + i * 16 + ((lane >> 4) << 2) + r;
            int nl = wn + j * 16 + (lane & 15);
            float v = acc[i][j][r] + biasv[n0 + nl];
            int byte_ = ml * 256 + ((nl * 2) ^ ((ml & 7) << 4));
            *(u16*)((char*)smem + byte_) = f2bf(v);
          }
        }
      }
      __syncthreads();
      const int row16 = tid >> 4, cch = tid & 15;
      const int mat = n0 >> 10;
      u16* Cd = (u16*)C + (long)mat * 4194304;
      #pragma unroll
      for (int rr = 0; rr < 8; rr++){
        int ml = rr * 16 + row16;
        short8_t vv = *(const short8_t*)((const char*)smem + ml * 256 + ((cch * 16) ^ ((ml & 7) << 4)));
        int m = m0 + ml;
        int np = (n0 & 1023) + cch * 8;
        long base = ((long)((m >> 10) * 16 + (np >> 6)) * 1024 + (m & 1023)) * 64 + (np & 63);
        *(short8_t*)(Cd + base) = vv;
      }
    }
    return;
  }
}

// ---------------- k_bias: EB[bhl][s][k] = EC[s][ix] * EP[k][ix] ----------------
__global__ __launch_bounds__(256, 2) void k_bias(
    const u16* __restrict__ EC, const u16* __restrict__ EP,
    const u16* __restrict__ T3, u16* __restrict__ EB, int bhbase)
{
  __shared__ __attribute__((aligned(16))) u16 C2W[2][8192];
  __shared__ __attribute__((aligned(16))) u16 P2W[2][8192];
  __shared__ __attribute__((aligned(16))) u16 IDW[2][128];
  const int flat0 = blockIdx.x;
  const int chunk = gridDim.x >> 3;
  const int flat = (flat0 & 7) * chunk + (flat0 >> 3);
  const int bhl = flat >> 5;
  const int sb  = (flat >> 1) & 15;
  const int kq  = flat & 1;
  const int bh = bhbase + bhl;
  const int tid = threadIdx.x, lane = tid & 63, w = tid >> 6;
  const int s0 = sb * 64;
  const u16* c2b = EC + (long)bh * 524288;
  const u16* p2b = EP + (long)bh * 524288;
  u16* EBb = EB + ((long)bhl << 20);

  const int r2 = tid >> 2;
  const int q2 = tid & 3;
  const int c2key = (r2 & 15) << 4;

  auto STAGE = [&](int buf, int t){
    const int ixlo = win_lo(s0, t);
    const int k0 = t * 64;
    #pragma unroll
    for (int r = 0; r < 16; r++){
      int row = w * 16 + r;
      const char* sa = (const char*)(c2b + (long)(s0 + row) * 512 + ixlo) + ((lane * 4) ^ ((row & 15) << 4));
      __builtin_amdgcn_global_load_lds((gas_ptr)sa, (las_ptr)((char*)&C2W[buf][0] + row * 256), 4, 0, 0);
      const char* sp = (const char*)(p2b + (long)(k0 + row) * 512 + ixlo) + ((lane * 4) ^ ((row & 15) << 4));
      __builtin_amdgcn_global_load_lds((gas_ptr)sp, (las_ptr)((char*)&P2W[buf][0] + row * 256), 4, 0, 0);
    }
    if (w == 3){
      int dev = s0 - k0 - 64;
      __builtin_amdgcn_global_load_lds((gas_ptr)((const char*)(T3 + (dev + 1024)) + lane * 4),
                                       (las_ptr)((char*)&IDW[buf][0]), 4, 0, 0);
    }
  };

  const int t0 = kq * 8;
  STAGE(0, t0);
  asm volatile("s_waitcnt vmcnt(0)" ::: "memory");
  __builtin_amdgcn_s_barrier();

  for (int i = 0; i < 8; i++){
    const int t = t0 + i, buf = i & 1;
    const int k0 = t * 64;
    const int ixlo = win_lo(s0, t);

    if (i < 7) STAGE(buf ^ 1, t + 1);

    u16 ov[16];
    #pragma unroll
    for (int c = 0; c < 16; c++){
      int kl = q2 * 16 + c;
      int j = r2 - kl + 64;
      int ix = (int)IDW[buf][j];
      int x = (ix - ixlo) * 2;
      float b1 = bf2f(*(const u16*)((const char*)&C2W[buf][0] + r2 * 256 + (x ^ c2key)));
      float b2 = bf2f(*(const u16*)((const char*)&P2W[buf][0] + kl * 256 + (x ^ ((kl & 15) << 4))));
      ov[c] = f2bf(b1 * b2);
    }
    u16* dst = EBb + (((long)(s0 + r2)) << 10) + k0 + q2 * 16;
    uint4 st0, st1;
    st0.x = (unsigned)ov[0]  | ((unsigned)ov[1]  << 16);
    st0.y = (unsigned)ov[2]  | ((unsigned)ov[3]  << 16);
    st0.z = (unsigned)ov[4]  | ((unsigned)ov[5]  << 16);
    st0.w = (unsigned)ov[6]  | ((unsigned)ov[7]  << 16);
    st1.x = (unsigned)ov[8]  | ((unsigned)ov[9]  << 16);
    st1.y = (unsigned)ov[10] | ((unsigned)ov[11] << 16);
    st1.z = (unsigned)ov[12] | ((unsigned)ov[13] << 16);
    st1.w = (unsigned)ov[14] | ((unsigned)ov[15] << 16);
    *(uint4*)dst = st0;
    *(uint4*)(dst + 8) = st1;

    if (i < 7){
      asm volatile("s_waitcnt vmcnt(2)" ::: "memory");
      __builtin_amdgcn_s_barrier();
    }
  }
}

// ---------------- k_attn_eb: streaming flash attn, bias pre-exp'd ----------------
__global__ __launch_bounds__(256, 3) void k_attn_eb(
    const u16* __restrict__ Q, const u16* __restrict__ K, const u16* __restrict__ Vt,
    const u16* __restrict__ EB, u16* __restrict__ ctx, int bhbase)
{
  __shared__ __attribute__((aligned(16))) u16 Ks[2][4096];
  __shared__ __attribute__((aligned(16))) u16 Vs[2][4096];
  __shared__ __attribute__((aligned(16))) u16 EBs[4096];
  __shared__ __attribute__((aligned(16))) u16 Pt[4096];
  const int flat0 = blockIdx.x;
  const int chunk = gridDim.x >> 3;
  const int flat = (flat0 & 7) * chunk + (flat0 >> 3);
  const int bhl = flat >> 4, sb = flat & 15;
  const int bh = bhbase + bhl;
  const int tid = threadIdx.x, lane = tid & 63, w = tid >> 6;
  const int s15 = lane & 15, g = lane >> 4;
  const int s0 = sb * 64;
  const int myrow = w * 16 + s15;
  const int s_row = s0 + myrow;
  const u16* Qb  = Q   + (long)bh * 65536;
  const u16* Kg  = K   + (long)bh * 65536;
  const u16* Vg  = Vt  + (long)bh * 65536;
  const u16* EBg = EB  + ((long)bhl << 20);

  short8_t qf0 = *(const short8_t*)(Qb + (long)s_row * 64 + g * 8);
  short8_t qf1 = *(const short8_t*)(Qb + (long)s_row * 64 + 32 + g * 8);

  const int srow8  = lane >> 3;
  const int schunk = (lane & 7) ^ srow8;
  const float sA2 = 0.10411754f;   // log2(e)/sqrt(192)

  auto STAGE_KV = [&](int buf, int kt){
    #pragma unroll
    for (int ii = 0; ii < 2; ii++){
      int i = w * 2 + ii;
      int row = i * 8 + srow8;
      __builtin_amdgcn_global_load_lds(
        (gas_ptr)((const char*)(Kg + (long)(kt + row) * 64) + schunk * 16),
        (las_ptr)((char*)&Ks[buf][0] + i * 1024), 16, 0, 0);
      __builtin_amdgcn_global_load_lds(
        (gas_ptr)((const char*)(Vg + (long)row * 1024 + kt) + schunk * 16),
        (las_ptr)((char*)&Vs[buf][0] + i * 1024), 16, 0, 0);
    }
  };
  auto STAGE_EB = [&](int kt){
    #pragma unroll
    for (int ii = 0; ii < 2; ii++){
      int rowl = w * 16 + ii * 8 + srow8;
      const char* src = (const char*)(EBg + (((long)(s0 + rowl)) << 10) + kt) + schunk * 16;
      __builtin_amdgcn_global_load_lds((gas_ptr)src,
        (las_ptr)((char*)EBs + (w * 2 + ii) * 1024), 16, 0, 0);
    }
  };

  STAGE_KV(0, 0);
  STAGE_EB(0);

  float rowsum = 0.f;
  floatx4 oacc[4];
  #pragma unroll
  for (int dt = 0; dt < 4; dt++) oacc[dt] = (floatx4){0.f, 0.f, 0.f, 0.f};

  const int psw = (myrow & 7) << 4;

  for (int t = 0; t < 16; t++){
    const int buf = t & 1;
    const int kt = t * 64;

    asm volatile("s_waitcnt vmcnt(2)" ::: "memory");
    asm volatile("s_waitcnt lgkmcnt(0)" ::: "memory");
    __builtin_amdgcn_s_barrier();

    STAGE_KV(buf ^ 1, (t < 15) ? kt + 64 : 0);

    floatx4 a[4];
    #pragma unroll
    for (int T = 0; T < 4; T++){
      int row = T * 16 + s15;
      const char* rp = (const char*)&Ks[buf][0] + row * 128;
      int sw = (row & 7) << 4;
      short8_t k0v = *(const short8_t*)(rp + ((g * 16) ^ sw));
      short8_t k1v = *(const short8_t*)(rp + ((64 + g * 16) ^ sw));
      floatx4 acc = (floatx4){0.f, 0.f, 0.f, 0.f};
      acc = __builtin_amdgcn_mfma_f32_16x16x32_bf16(k0v, qf0, acc, 0, 0, 0);
      acc = __builtin_amdgcn_mfma_f32_16x16x32_bf16(k1v, qf1, acc, 0, 0, 0);
      a[T] = acc;
    }

    asm volatile("s_waitcnt vmcnt(4)" ::: "memory");

    #pragma unroll
    for (int T = 0; T < 4; T++){
      uint2 ebv = *(const uint2*)((const char*)EBs + myrow * 128 + ((T * 32 + g * 8) ^ psw));
      float e0 = exp2f(a[T][0] * sA2) * bf2f((u16)(ebv.x & 0xffff));
      float e1 = exp2f(a[T][1] * sA2) * bf2f((u16)(ebv.x >> 16));
      float e2 = exp2f(a[T][2] * sA2) * bf2f((u16)(ebv.y & 0xffff));
      float e3 = exp2f(a[T][3] * sA2) * bf2f((u16)(ebv.y >> 16));
      u16 p0 = f2bf(e0), p1 = f2bf(e1), p2v = f2bf(e2), p3 = f2bf(e3);
      rowsum += (bf2f(p0) + bf2f(p1)) + (bf2f(p2v) + bf2f(p3));
      uint2 pk2;
      pk2.x = (unsigned)p0  | ((unsigned)p1 << 16);
      pk2.y = (unsigned)p2v | ((unsigned)p3 << 16);
      *(uint2*)((char*)Pt + myrow * 128 + ((T * 32 + g * 8) ^ psw)) = pk2;
    }

    asm volatile("s_waitcnt lgkmcnt(0)" ::: "memory");
    STAGE_EB((t < 15) ? kt + 64 : 0);

    #pragma unroll
    for (int M = 0; M < 2; M++){
      short8_t pf = *(const short8_t*)((const char*)Pt + myrow * 128 + ((M * 64 + g * 16) ^ psw));
      #pragma unroll
      for (int dt = 0; dt < 4; dt++){
        int drow = dt * 16 + s15;
        short8_t vf = *(const short8_t*)((const char*)&Vs[buf][0] + drow * 128 + ((M * 64 + g * 16) ^ ((drow & 7) << 4)));
        oacc[dt] = __builtin_amdgcn_mfma_f32_16x16x32_bf16(pf, vf, oacc[dt], 0, 0, 0);
      }
    }
  }

  asm volatile("s_waitcnt vmcnt(0)" ::: "memory");

  rowsum += __shfl_xor(rowsum, 16);
  rowsum += __shfl_xor(rowsum, 32);
  float rinv = 1.f / rowsum;

  const int b = bh >> 4, h = bh & 15;
  #pragma unroll
  for (int r = 0; r < 4; r++){
    float ri = __shfl(rinv, g * 4 + r);
    int s_out = s0 + w * 16 + g * 4 + r;
    #pragma unroll
    for (int dt = 0; dt < 4; dt++){
      long oi = ((long)b * 1024 + s_out) * 1024 + h * 64 + dt * 16 + s15;
      ctx[oi] = f2bf(oacc[dt][r] * ri);
    }
  }
}

// ---------------- launch ----------------
extern "C" void kernel_launch(void* const* d_in, const int* in_sizes, int n_in,
                              void* d_out, int out_size, void* d_ws, size_t ws_size,
                              hipStream_t stream){
  const float* hs  = (const float*)d_in[0];
  const float* Wq  = (const float*)d_in[1];
  const float* bq  = (const float*)d_in[2];
  const float* Wk  = (const float*)d_in[3];
  const float* bk  = (const float*)d_in[4];
  const float* Wv  = (const float*)d_in[5];
  const float* bv  = (const float*)d_in[6];
  const float* Wo  = (const float*)d_in[7];
  const float* bo  = (const float*)d_in[8];
  const float* rel = (const float*)d_in[9];
  const float* lng = (const float*)d_in[10];
  const float* lnb = (const float*)d_in[11];
  const float* Wpk = (const float*)d_in[12];
  const float* bpk = (const float*)d_in[13];
  const float* Wpq = (const float*)d_in[14];
  const float* bpq = (const float*)d_in[15];

  char* ws = (char*)d_ws;
  size_t off = 0;
  auto alloc = [&](size_t bytes){ size_t o = off; off += (bytes + 255) & ~(size_t)255; return o; };
  // ---- live-through-end region ----
  u16* Wo_t  = (u16*)(ws + alloc(1048576UL * 2));
  u16* Qd    = (u16*)(ws + alloc(4194304UL * 2));
  u16* Kd    = (u16*)(ws + alloc(4194304UL * 2));
  u16* Vtd   = (u16*)(ws + alloc(4194304UL * 2));
  u16* ECd   = (u16*)(ws + alloc(33554432UL * 2));
  u16* EPd   = (u16*)(ws + alloc(33554432UL * 2));
  u16* ctx   = (u16*)(ws + alloc(4194304UL * 2));
  u16* idxt  = (u16*)(ws + alloc(2048UL * 2));
  float* qkvb = (float*)(ws + alloc(3072UL * 4));
  float* posb = (float*)(ws + alloc(2048UL * 4));
  // ---- dead-after-EC/EP-GEMM region (EB aliases from here) ----
  size_t dead0 = off;
  u16* h_bf  = (u16*)(ws + alloc(4194304UL * 2));
  u16* Wt5   = (u16*)(ws + alloc(5UL * 1048576 * 2));
  u16* re_bf = (u16*)(ws + alloc(524288UL * 2));
  u16* posk  = (u16*)(ws + alloc(524288UL * 2));
  u16* posq  = (u16*)(ws + alloc(524288UL * 2));
  u16* EB    = (u16*)(ws + dead0);
  const bool full = (ws_size >= dead0 + 134217728UL);
  (void)posq; (void)Kd;

  k_prep<<<6145, 256, 0, stream>>>(hs, Wq, Wk, Wv, Wpk, Wpq, Wo, rel, lng, lnb,
                                   bq, bk, bv, bpk, bpq,
                                   h_bf, Wt5, Wo_t, re_bf, idxt, qkvb, posb);

  // fused QKV (XCD-swizzled, by<32) + pos GEMM (by in [32,36), bx<16)
  k_gemm<5><<<dim3(24, 36, 1), 256, 0, stream>>>(h_bf, Wt5, qkvb, Qd, Vtd,
                                                 4096, 3072, 1024, 1024, 1024,
                                                 re_bf, posb, posk);
  // EC (z<64) / EP (z>=64), batched over bh; epilogue applies exp2
  k_gemm<4><<<dim3(4, 8, 128), 256, 0, stream>>>(Qd, posk, nullptr, ECd, nullptr,
                                                 1024, 512, 64, 64, 64,
                                                 nullptr, nullptr, nullptr);

  if (full){
    k_bias   <<<dim3(2048), 256, 0, stream>>>(ECd, EPd, idxt, EB, 0);
    k_attn_eb<<<dim3(1024), 256, 0, stream>>>(Qd, Kd, Vtd, EB, ctx, 0);
  } else {
    k_bias   <<<dim3(1024), 256, 0, stream>>>(ECd, EPd, idxt, EB, 0);
    k_attn_eb<<<dim3(512),  256, 0, stream>>>(Qd, Kd, Vtd, EB, ctx, 0);
    k_bias   <<<dim3(1024), 256, 0, stream>>>(ECd, EPd, idxt, EB, 32);
    k_attn_eb<<<dim3(512),  256, 0, stream>>>(Qd, Kd, Vtd, EB, ctx, 32);
  }

  // output projection (f32 out, XCD-swizzled)
  k_gemm<0><<<dim3(8, 32, 1), 256, 0, stream>>>(ctx, Wo_t, bo, d_out, nullptr,
                                                4096, 1024, 1024, 1024, 1024,
                                                nullptr, nullptr, nullptr);
}

// Round 12
// 238.555 us; speedup vs baseline: 1.9040x; 1.0847x over previous
//
#include <hip/hip_runtime.h>

typedef unsigned short u16;
typedef __attribute__((ext_vector_type(8))) short short8_t;
typedef __attribute__((ext_vector_type(4))) float floatx4;

typedef const void __attribute__((address_space(1)))* gas_ptr;
typedef void __attribute__((address_space(3)))* las_ptr;

__device__ __forceinline__ float bf2f(u16 u){
  union { unsigned i; float f; } v; v.i = ((unsigned)u) << 16; return v.f;
}
__device__ __forceinline__ u16 f2bf(float x){
  unsigned u = __float_as_uint(x);
  return (u16)((u + 0x7FFFu + ((u >> 16) & 1u)) >> 16);
}
__device__ __forceinline__ int bucket_idx(int delta){
  int b;
  if (delta >= -128 && delta <= 128) b = delta;
  else {
    float a = (float)(delta < 0 ? -delta : delta);
    float lp = ceilf(logf(a * (1.0f / 128.0f)) / logf(511.0f / 128.0f) * 127.0f) + 128.0f;
    b = (int)lp;
    if (delta < 0) b = -b;
  }
  int idx = b + 256;
  return idx < 0 ? 0 : (idx > 511 ? 511 : idx);
}
__device__ __forceinline__ int win_lo(int s0, int t){
  int dlo = s0 - t * 64 - 63;
  int lo = bucket_idx(dlo) & ~1;
  return lo > 384 ? 384 : lo;
}

// ---------------- fused prep kernel ----------------
__global__ __launch_bounds__(256) void k_prep(
    const float* __restrict__ hs,
    const float* __restrict__ W0, const float* __restrict__ W1, const float* __restrict__ W2,
    const float* __restrict__ W3, const float* __restrict__ W4, const float* __restrict__ W5,
    const float* __restrict__ rel, const float* __restrict__ lng, const float* __restrict__ lnb,
    const float* __restrict__ bq, const float* __restrict__ bk, const float* __restrict__ bv,
    const float* __restrict__ bpk, const float* __restrict__ bpq,
    u16* __restrict__ h_bf, u16* __restrict__ Wt5, u16* __restrict__ Wo_t,
    u16* __restrict__ re_bf, u16* __restrict__ idxt,
    float* __restrict__ qkvb, float* __restrict__ posb)
{
  __shared__ float t[64][65];
  const int bid = blockIdx.x, tid = threadIdx.x;
  if (bid < 4096){
    int i = bid * 256 + tid;
    float4 v = ((const float4*)hs)[i];
    ushort4 o;
    o.x = f2bf(v.x); o.y = f2bf(v.y); o.z = f2bf(v.z); o.w = f2bf(v.w);
    ((ushort4*)h_bf)[i] = o;
  } else if (bid < 5632){
    int b2 = bid - 4096;
    int z = b2 >> 8, rem = b2 & 255;
    const float* W = (z == 0) ? W0 : (z == 1) ? W1 : (z == 2) ? W2 : (z == 3) ? W3 : (z == 4) ? W4 : W5;
    u16* Wt = (z < 5) ? (Wt5 + (long)z * 1048576) : Wo_t;
    int n0 = (rem & 15) * 64, k0 = (rem >> 4) * 64;
    #pragma unroll
    for (int i = 0; i < 16; i++){
      int e = i * 256 + tid; int r = e >> 6, c = e & 63;
      t[r][c] = W[(long)(k0 + r) * 1024 + n0 + c];
    }
    __syncthreads();
    #pragma unroll
    for (int i = 0; i < 16; i++){
      int e = i * 256 + tid; int r = e >> 6, c = e & 63;
      Wt[(long)(n0 + r) * 1024 + k0 + c] = f2bf(t[c][r]);
    }
  } else if (bid < 6144){
    int row = bid - 5632;
    float* red = (float*)t;
    float4 v = ((const float4*)(rel + (long)row * 1024))[tid];
    float s  = v.x + v.y + v.z + v.w;
    float s2 = v.x*v.x + v.y*v.y + v.z*v.z + v.w*v.w;
    #pragma unroll
    for (int o = 1; o < 64; o <<= 1){ s += __shfl_xor(s, o); s2 += __shfl_xor(s2, o); }
    if ((tid & 63) == 0){ red[(tid >> 6) * 2] = s; red[(tid >> 6) * 2 + 1] = s2; }
    __syncthreads();
    s  = red[0] + red[2] + red[4] + red[6];
    s2 = red[1] + red[3] + red[5] + red[7];
    float mu  = s * (1.f / 1024.f);
    float var = s2 * (1.f / 1024.f) - mu * mu;
    float rs  = rsqrtf(var + 1e-5f);
    float4 gg = ((const float4*)lng)[tid];
    float4 bb = ((const float4*)lnb)[tid];
    ushort4 o;
    o.x = f2bf((v.x - mu) * rs * gg.x + bb.x);
    o.y = f2bf((v.y - mu) * rs * gg.y + bb.y);
    o.z = f2bf((v.z - mu) * rs * gg.z + bb.z);
    o.w = f2bf((v.w - mu) * rs * gg.w + bb.w);
    ((ushort4*)(re_bf + (long)row * 1024))[tid] = o;
  } else {
    for (int i = tid; i < 2048; i += 256)
      idxt[i] = (u16)bucket_idx(i - 1024);
    for (int i = tid; i < 1024; i += 256){
      qkvb[i] = bq[i]; qkvb[1024 + i] = bk[i]; qkvb[2048 + i] = bv[i];
      posb[i] = bpk[i]; posb[1024 + i] = bpq[i];
    }
  }
}

// ---------------- MFMA GEMM ----------------
// MODE 0: f32 rowmajor (LDS-bounce, XCD-swizzled, 2-deep counted pipeline)
// MODE 4: EC/EP batched z in [0,128): exp2(v*sB2), LDS-bounce (K=64, single tile)
// MODE 5: fused QKV N=3072 (2D-XCD-chunked, 2-deep pipeline) + pos GEMM at by>=32
// Dynamic LDS: 64KB for MODE 0/5 (double-buffered), 32KB for MODE 4.
template<int MODE>
__global__ __launch_bounds__(256) void k_gemm(
    const u16* __restrict__ A, const u16* __restrict__ Bt,
    const float* __restrict__ bias, void* __restrict__ C, void* __restrict__ C2,
    int M, int N, int K, int lda, int ldb,
    const u16* __restrict__ Apos, const float* __restrict__ biaspos, void* __restrict__ Cpos)
{
  extern __shared__ __attribute__((aligned(16))) u16 smem[];
  const int bx = blockIdx.x, by = blockIdx.y;
  const int z = blockIdx.z;
  const u16* Ab = A;
  const u16* Bb = Bt;
  const float* biasv = bias;
  bool pospath = false;
  int pz = 0;
  int m0, n0;
  if (MODE == 5){
    if (by >= 32){
      if (bx >= 16) return;
      pospath = true;
      pz = bx >> 3;
      Ab = Apos;
      Bb = Bt + 3145728 + (long)pz * 1048576;
      biasv = biaspos + (pz << 10);
      m0 = (by - 32) * 128;
      n0 = (bx & 7) * 128;
    } else {
      // 2D XCD chunking: 768 blocks -> 8 XCD rectangles of 8m x 12n panels
      int bid = by * 24 + bx;
      int xcd = bid & 7, r = bid >> 3;        // r in [0,96)
      int cm = xcd >> 1, cn = xcd & 1;
      m0 = (cm * 8 + r / 12) * 128;
      n0 = (cn * 12 + r % 12) * 128;
    }
  } else if (MODE == 0){
    // 256 = 8 x 32; each XCD owns 4 contiguous m-panels x all 8 n
    int bid = by * 8 + bx;
    int nf = (bid & 7) * 32 + (bid >> 3);
    m0 = (nf >> 3) * 128;
    n0 = (nf & 7) * 128;
  } else {
    if (MODE == 4){ Ab = A + (long)z * 65536; Bb = Bt + (long)(z >> 6) * 524288 + (long)(z & 15) * 32768; }
    m0 = by * 128;
    n0 = bx * 128;
  }
  const int tid = threadIdx.x, lane = tid & 63, w = tid >> 6;
  const int wm = (w >> 1) * 64, wn = (w & 1) * 64;
  floatx4 acc[4][4];
  #pragma unroll
  for (int i = 0; i < 4; i++)
    #pragma unroll
    for (int j = 0; j < 4; j++) acc[i][j] = (floatx4){0.f, 0.f, 0.f, 0.f};

  const int r8 = lane >> 3;
  const int cswz = ((lane & 7) ^ r8) << 4;

  auto STAGE = [&](int buf, int kt){
    u16* As = smem + buf * 16384;
    u16* Bs = As + 8192;
    #pragma unroll
    for (int c = 0; c < 4; c++){
      int row = (c * 4 + w) * 8 + r8;
      const char* ga = (const char*)(Ab + (long)(m0 + row) * lda + kt) + cswz;
      __builtin_amdgcn_global_load_lds((gas_ptr)ga, (las_ptr)((char*)As + (c * 4 + w) * 1024), 16, 0, 0);
      const char* gb = (const char*)(Bb + (long)(n0 + row) * ldb + kt) + cswz;
      __builtin_amdgcn_global_load_lds((gas_ptr)gb, (las_ptr)((char*)Bs + (c * 4 + w) * 1024), 16, 0, 0);
    }
  };
  auto COMPUTE = [&](int buf){
    const u16* As = smem + buf * 16384;
    const u16* Bs = As + 8192;
    short8_t af[2][4], bfr[2][4];
    #pragma unroll
    for (int kk = 0; kk < 2; kk++){
      #pragma unroll
      for (int i = 0; i < 4; i++){
        int ra = wm + i * 16 + (lane & 15);
        af[kk][i] = *(const short8_t*)((const char*)As + ra * 128 + ((kk * 64 + ((lane >> 4) << 4)) ^ ((ra & 7) << 4)));
        int rb = wn + i * 16 + (lane & 15);
        bfr[kk][i] = *(const short8_t*)((const char*)Bs + rb * 128 + ((kk * 64 + ((lane >> 4) << 4)) ^ ((rb & 7) << 4)));
      }
    }
    #pragma unroll
    for (int i = 0; i < 4; i++)
      #pragma unroll
      for (int j = 0; j < 4; j++){
        acc[i][j] = __builtin_amdgcn_mfma_f32_16x16x32_bf16(af[0][i], bfr[0][j], acc[i][j], 0, 0, 0);
        acc[i][j] = __builtin_amdgcn_mfma_f32_16x16x32_bf16(af[1][i], bfr[1][j], acc[i][j], 0, 0, 0);
      }
  };

  if (MODE == 4){
    // K=64: single tile, simple structure
    STAGE(0, 0);
    __syncthreads();
    COMPUTE(0);
    __syncthreads();
  } else {
    // 2-deep counted pipeline: loads stay in flight across barriers, never drain mid-loop
    const int T = K >> 6;
    STAGE(0, 0);
    STAGE(1, 64);
    for (int t = 0; t < T; t++){
      const int buf = t & 1;
      if (t < T - 1) asm volatile("s_waitcnt vmcnt(8)" ::: "memory");   // stage(t) landed; stage(t+1) in flight
      else           asm volatile("s_waitcnt vmcnt(0)" ::: "memory");   // tail: only stage(T-1) outstanding
      __builtin_amdgcn_s_barrier();
      COMPUTE(buf);
      __builtin_amdgcn_s_barrier();                                     // all waves done reading buf
      if (t < T - 2) STAGE(buf, (t + 2) << 6);                          // overwrite safe; lands by t+2
    }
  }

  if (MODE == 0){
    // f32 out via LDS bounce, two 128x64 halves
    float* fs = (float*)smem;
    #pragma unroll
    for (int h = 0; h < 2; h++){
      if ((w & 1) == h){
        #pragma unroll
        for (int i = 0; i < 4; i++)
          #pragma unroll
          for (int j = 0; j < 4; j++)
            #pragma unroll
            for (int r = 0; r < 4; r++){
              int ml = wm + i * 16 + ((lane >> 4) << 2) + r;
              int nl = j * 16 + (lane & 15);
              fs[ml * 64 + (nl ^ (((ml >> 2) & 3) << 4))] = acc[i][j][r] + biasv[n0 + h * 64 + nl];
            }
      }
      __syncthreads();
      const int row16 = tid >> 4, cch = tid & 15;
      #pragma unroll
      for (int rr = 0; rr < 8; rr++){
        int ml = rr * 16 + row16;
        float4 vv = *(const float4*)&fs[ml * 64 + ((cch * 4) ^ (((ml >> 2) & 3) << 4))];
        *(float4*)((float*)C + (long)(m0 + ml) * N + n0 + h * 64 + cch * 4) = vv;
      }
      __syncthreads();
    }
    return;
  }

  if (MODE == 4){
    // exp2 + bf16 into LDS (swizzled), then coalesced short8 row stores
    #pragma unroll
    for (int i = 0; i < 4; i++){
      #pragma unroll
      for (int j = 0; j < 4; j++){
        #pragma unroll
        for (int r = 0; r < 4; r++){
          int ml = wm + i * 16 + ((lane >> 4) << 2) + r;
          int nl = wn + j * 16 + (lane & 15);
          int byte_ = ml * 256 + ((nl * 2) ^ ((ml & 7) << 4));
          *(u16*)((char*)smem + byte_) = f2bf(exp2f(acc[i][j][r] * 0.12751743f));
        }
      }
    }
    __syncthreads();
    const int row16 = tid >> 4, cch = tid & 15;
    #pragma unroll
    for (int rr = 0; rr < 8; rr++){
      int ml = rr * 16 + row16;
      short8_t vv = *(const short8_t*)((const char*)smem + ml * 256 + ((cch * 16) ^ ((ml & 7) << 4)));
      *(short8_t*)((u16*)C + (long)z * 524288 + (long)(m0 + ml) * 512 + n0 + cch * 8) = vv;
    }
    return;
  }

  if (MODE == 5){
    if (pospath){
      // pos GEMM epilogue: [pz][h][512][64], scalar (tiny: 64 blocks)
      #pragma unroll
      for (int i = 0; i < 4; i++){
        #pragma unroll
        for (int j = 0; j < 4; j++){
          #pragma unroll
          for (int r = 0; r < 4; r++){
            int m = m0 + wm + i * 16 + ((lane >> 4) << 2) + r;
            int n = n0 + wn + j * 16 + (lane & 15);
            float v = acc[i][j][r] + biasv[n];
            ((u16*)Cpos)[(long)pz * 524288 + ((long)(n >> 6) * 512 + m) * 64 + (n & 63)] = f2bf(v);
          }
        }
      }
      return;
    }
    if (n0 >= 2048){
      // V^T via LDS-bounce (transposed tile), coalesced along s
      #pragma unroll
      for (int i = 0; i < 4; i++){
        #pragma unroll
        for (int j = 0; j < 4; j++){
          #pragma unroll
          for (int r = 0; r < 4; r++){
            int ml = wm + i * 16 + ((lane >> 4) << 2) + r;
            int nl = wn + j * 16 + (lane & 15);
            float v = acc[i][j][r] + biasv[n0 + nl];
            int byte_ = nl * 256 + ((ml * 2) ^ ((nl & 7) << 4));
            *(u16*)((char*)smem + byte_) = f2bf(v);
          }
        }
      }
      __syncthreads();
      #pragma unroll
      for (int rr = 0; rr < 8; rr++){
        int nl = rr * 16 + (tid >> 4);
        int np = n0 + nl - 2048;
        int mc = tid & 15;
        short8_t vv = *(const short8_t*)((const char*)smem + nl * 256 + ((mc * 16) ^ ((nl & 7) << 4)));
        int m = m0 + mc * 8;
        long base = ((long)((m >> 10) * 16 + (np >> 6)) * 64 + (np & 63)) * 1024 + (m & 1023);
        *(short8_t*)((u16*)C2 + base) = vv;
      }
    } else {
      // Q/K via LDS-bounce (row-major tile), coalesced along d within head
      #pragma unroll
      for (int i = 0; i < 4; i++){
        #pragma unroll
        for (int j = 0; j < 4; j++){
          #pragma unroll
          for (int r = 0; r < 4; r++){
            int ml = wm + i * 16 + ((lane >> 4) << 2) + r;
            int nl = wn + j * 16 + (lane & 15);
            float v = acc[i][j][r] + biasv[n0 + nl];
            int byte_ = ml * 256 + ((nl * 2) ^ ((ml & 7) << 4));
            *(u16*)((char*)smem + byte_) = f2bf(v);
          }
        }
      }
      __syncthreads();
      const int row16 = tid >> 4, cch = tid & 15;
      const int mat = n0 >> 10;
      u16* Cd = (u16*)C + (long)mat * 4194304;
      #pragma unroll
      for (int rr = 0; rr < 8; rr++){
        int ml = rr * 16 + row16;
        short8_t vv = *(const short8_t*)((const char*)smem + ml * 256 + ((cch * 16) ^ ((ml & 7) << 4)));
        int m = m0 + ml;
        int np = (n0 & 1023) + cch * 8;
        long base = ((long)((m >> 10) * 16 + (np >> 6)) * 1024 + (m & 1023)) * 64 + (np & 63);
        *(short8_t*)(Cd + base) = vv;
      }
    }
    return;
  }
}

// ---------------- k_bias: EB[bhl][s][k] = EC[s][ix] * EP[k][ix] ----------------
__global__ __launch_bounds__(256, 2) void k_bias(
    const u16* __restrict__ EC, const u16* __restrict__ EP,
    const u16* __restrict__ T3, u16* __restrict__ EB, int bhbase)
{
  __shared__ __attribute__((aligned(16))) u16 C2W[2][8192];
  __shared__ __attribute__((aligned(16))) u16 P2W[2][8192];
  __shared__ __attribute__((aligned(16))) u16 IDW[2][128];
  const int flat0 = blockIdx.x;
  const int chunk = gridDim.x >> 3;
  const int flat = (flat0 & 7) * chunk + (flat0 >> 3);
  const int bhl = flat >> 5;
  const int sb  = (flat >> 1) & 15;
  const int kq  = flat & 1;
  const int bh = bhbase + bhl;
  const int tid = threadIdx.x, lane = tid & 63, w = tid >> 6;
  const int s0 = sb * 64;
  const u16* c2b = EC + (long)bh * 524288;
  const u16* p2b = EP + (long)bh * 524288;
  u16* EBb = EB + ((long)bhl << 20);

  const int r2 = tid >> 2;
  const int q2 = tid & 3;
  const int c2key = (r2 & 15) << 4;

  auto STAGE = [&](int buf, int t){
    const int ixlo = win_lo(s0, t);
    const int k0 = t * 64;
    #pragma unroll
    for (int r = 0; r < 16; r++){
      int row = w * 16 + r;
      const char* sa = (const char*)(c2b + (long)(s0 + row) * 512 + ixlo) + ((lane * 4) ^ ((row & 15) << 4));
      __builtin_amdgcn_global_load_lds((gas_ptr)sa, (las_ptr)((char*)&C2W[buf][0] + row * 256), 4, 0, 0);
      const char* sp = (const char*)(p2b + (long)(k0 + row) * 512 + ixlo) + ((lane * 4) ^ ((row & 15) << 4));
      __builtin_amdgcn_global_load_lds((gas_ptr)sp, (las_ptr)((char*)&P2W[buf][0] + row * 256), 4, 0, 0);
    }
    if (w == 3){
      int dev = s0 - k0 - 64;
      __builtin_amdgcn_global_load_lds((gas_ptr)((const char*)(T3 + (dev + 1024)) + lane * 4),
                                       (las_ptr)((char*)&IDW[buf][0]), 4, 0, 0);
    }
  };

  const int t0 = kq * 8;
  STAGE(0, t0);
  asm volatile("s_waitcnt vmcnt(0)" ::: "memory");
  __builtin_amdgcn_s_barrier();

  for (int i = 0; i < 8; i++){
    const int t = t0 + i, buf = i & 1;
    const int k0 = t * 64;
    const int ixlo = win_lo(s0, t);

    if (i < 7) STAGE(buf ^ 1, t + 1);

    u16 ov[16];
    #pragma unroll
    for (int c = 0; c < 16; c++){
      int kl = q2 * 16 + c;
      int j = r2 - kl + 64;
      int ix = (int)IDW[buf][j];
      int x = (ix - ixlo) * 2;
      float b1 = bf2f(*(const u16*)((const char*)&C2W[buf][0] + r2 * 256 + (x ^ c2key)));
      float b2 = bf2f(*(const u16*)((const char*)&P2W[buf][0] + kl * 256 + (x ^ ((kl & 15) << 4))));
      ov[c] = f2bf(b1 * b2);
    }
    u16* dst = EBb + (((long)(s0 + r2)) << 10) + k0 + q2 * 16;
    uint4 st0, st1;
    st0.x = (unsigned)ov[0]  | ((unsigned)ov[1]  << 16);
    st0.y = (unsigned)ov[2]  | ((unsigned)ov[3]  << 16);
    st0.z = (unsigned)ov[4]  | ((unsigned)ov[5]  << 16);
    st0.w = (unsigned)ov[6]  | ((unsigned)ov[7]  << 16);
    st1.x = (unsigned)ov[8]  | ((unsigned)ov[9]  << 16);
    st1.y = (unsigned)ov[10] | ((unsigned)ov[11] << 16);
    st1.z = (unsigned)ov[12] | ((unsigned)ov[13] << 16);
    st1.w = (unsigned)ov[14] | ((unsigned)ov[15] << 16);
    *(uint4*)dst = st0;
    *(uint4*)(dst + 8) = st1;

    if (i < 7){
      asm volatile("s_waitcnt vmcnt(2)" ::: "memory");
      __builtin_amdgcn_s_barrier();
    }
  }
}

// ---------------- k_attn_eb: streaming flash attn, bias pre-exp'd ----------------
__global__ __launch_bounds__(256, 3) void k_attn_eb(
    const u16* __restrict__ Q, const u16* __restrict__ K, const u16* __restrict__ Vt,
    const u16* __restrict__ EB, u16* __restrict__ ctx, int bhbase)
{
  __shared__ __attribute__((aligned(16))) u16 Ks[2][4096];
  __shared__ __attribute__((aligned(16))) u16 Vs[2][4096];
  __shared__ __attribute__((aligned(16))) u16 EBs[4096];
  __shared__ __attribute__((aligned(16))) u16 Pt[4096];
  const int flat0 = blockIdx.x;
  const int chunk = gridDim.x >> 3;
  const int flat = (flat0 & 7) * chunk + (flat0 >> 3);
  const int bhl = flat >> 4, sb = flat & 15;
  const int bh = bhbase + bhl;
  const int tid = threadIdx.x, lane = tid & 63, w = tid >> 6;
  const int s15 = lane & 15, g = lane >> 4;
  const int s0 = sb * 64;
  const int myrow = w * 16 + s15;
  const int s_row = s0 + myrow;
  const u16* Qb  = Q   + (long)bh * 65536;
  const u16* Kg  = K   + (long)bh * 65536;
  const u16* Vg  = Vt  + (long)bh * 65536;
  const u16* EBg = EB  + ((long)bhl << 20);

  short8_t qf0 = *(const short8_t*)(Qb + (long)s_row * 64 + g * 8);
  short8_t qf1 = *(const short8_t*)(Qb + (long)s_row * 64 + 32 + g * 8);

  const int srow8  = lane >> 3;
  const int schunk = (lane & 7) ^ srow8;
  const float sA2 = 0.10411754f;   // log2(e)/sqrt(192)

  auto STAGE_KV = [&](int buf, int kt){
    #pragma unroll
    for (int ii = 0; ii < 2; ii++){
      int i = w * 2 + ii;
      int row = i * 8 + srow8;
      __builtin_amdgcn_global_load_lds(
        (gas_ptr)((const char*)(Kg + (long)(kt + row) * 64) + schunk * 16),
        (las_ptr)((char*)&Ks[buf][0] + i * 1024), 16, 0, 0);
      __builtin_amdgcn_global_load_lds(
        (gas_ptr)((const char*)(Vg + (long)row * 1024 + kt) + schunk * 16),
        (las_ptr)((char*)&Vs[buf][0] + i * 1024), 16, 0, 0);
    }
  };
  auto STAGE_EB = [&](int kt){
    #pragma unroll
    for (int ii = 0; ii < 2; ii++){
      int rowl = w * 16 + ii * 8 + srow8;
      const char* src = (const char*)(EBg + (((long)(s0 + rowl)) << 10) + kt) + schunk * 16;
      __builtin_amdgcn_global_load_lds((gas_ptr)src,
        (las_ptr)((char*)EBs + (w * 2 + ii) * 1024), 16, 0, 0);
    }
  };

  STAGE_KV(0, 0);
  STAGE_EB(0);

  float rowsum = 0.f;
  floatx4 oacc[4];
  #pragma unroll
  for (int dt = 0; dt < 4; dt++) oacc[dt] = (floatx4){0.f, 0.f, 0.f, 0.f};

  const int psw = (myrow & 7) << 4;

  for (int t = 0; t < 16; t++){
    const int buf = t & 1;
    const int kt = t * 64;

    asm volatile("s_waitcnt vmcnt(2)" ::: "memory");
    asm volatile("s_waitcnt lgkmcnt(0)" ::: "memory");
    __builtin_amdgcn_s_barrier();

    STAGE_KV(buf ^ 1, (t < 15) ? kt + 64 : 0);

    floatx4 a[4];
    #pragma unroll
    for (int T = 0; T < 4; T++){
      int row = T * 16 + s15;
      const char* rp = (const char*)&Ks[buf][0] + row * 128;
      int sw = (row & 7) << 4;
      short8_t k0v = *(const short8_t*)(rp + ((g * 16) ^ sw));
      short8_t k1v = *(const short8_t*)(rp + ((64 + g * 16) ^ sw));
      floatx4 acc = (floatx4){0.f, 0.f, 0.f, 0.f};
      acc = __builtin_amdgcn_mfma_f32_16x16x32_bf16(k0v, qf0, acc, 0, 0, 0);
      acc = __builtin_amdgcn_mfma_f32_16x16x32_bf16(k1v, qf1, acc, 0, 0, 0);
      a[T] = acc;
    }

    asm volatile("s_waitcnt vmcnt(4)" ::: "memory");

    #pragma unroll
    for (int T = 0; T < 4; T++){
      uint2 ebv = *(const uint2*)((const char*)EBs + myrow * 128 + ((T * 32 + g * 8) ^ psw));
      float e0 = exp2f(a[T][0] * sA2) * bf2f((u16)(ebv.x & 0xffff));
      float e1 = exp2f(a[T][1] * sA2) * bf2f((u16)(ebv.x >> 16));
      float e2 = exp2f(a[T][2] * sA2) * bf2f((u16)(ebv.y & 0xffff));
      float e3 = exp2f(a[T][3] * sA2) * bf2f((u16)(ebv.y >> 16));
      u16 p0 = f2bf(e0), p1 = f2bf(e1), p2v = f2bf(e2), p3 = f2bf(e3);
      rowsum += (bf2f(p0) + bf2f(p1)) + (bf2f(p2v) + bf2f(p3));
      uint2 pk2;
      pk2.x = (unsigned)p0  | ((unsigned)p1 << 16);
      pk2.y = (unsigned)p2v | ((unsigned)p3 << 16);
      *(uint2*)((char*)Pt + myrow * 128 + ((T * 32 + g * 8) ^ psw)) = pk2;
    }

    asm volatile("s_waitcnt lgkmcnt(0)" ::: "memory");
    STAGE_EB((t < 15) ? kt + 64 : 0);

    #pragma unroll
    for (int M = 0; M < 2; M++){
      short8_t pf = *(const short8_t*)((const char*)Pt + myrow * 128 + ((M * 64 + g * 16) ^ psw));
      #pragma unroll
      for (int dt = 0; dt < 4; dt++){
        int drow = dt * 16 + s15;
        short8_t vf = *(const short8_t*)((const char*)&Vs[buf][0] + drow * 128 + ((M * 64 + g * 16) ^ ((drow & 7) << 4)));
        oacc[dt] = __builtin_amdgcn_mfma_f32_16x16x32_bf16(pf, vf, oacc[dt], 0, 0, 0);
      }
    }
  }

  asm volatile("s_waitcnt vmcnt(0)" ::: "memory");

  rowsum += __shfl_xor(rowsum, 16);
  rowsum += __shfl_xor(rowsum, 32);
  float rinv = 1.f / rowsum;

  const int b = bh >> 4, h = bh & 15;
  #pragma unroll
  for (int r = 0; r < 4; r++){
    float ri = __shfl(rinv, g * 4 + r);
    int s_out = s0 + w * 16 + g * 4 + r;
    #pragma unroll
    for (int dt = 0; dt < 4; dt++){
      long oi = ((long)b * 1024 + s_out) * 1024 + h * 64 + dt * 16 + s15;
      ctx[oi] = f2bf(oacc[dt][r] * ri);
    }
  }
}

// ---------------- launch ----------------
extern "C" void kernel_launch(void* const* d_in, const int* in_sizes, int n_in,
                              void* d_out, int out_size, void* d_ws, size_t ws_size,
                              hipStream_t stream){
  const float* hs  = (const float*)d_in[0];
  const float* Wq  = (const float*)d_in[1];
  const float* bq  = (const float*)d_in[2];
  const float* Wk  = (const float*)d_in[3];
  const float* bk  = (const float*)d_in[4];
  const float* Wv  = (const float*)d_in[5];
  const float* bv  = (const float*)d_in[6];
  const float* Wo  = (const float*)d_in[7];
  const float* bo  = (const float*)d_in[8];
  const float* rel = (const float*)d_in[9];
  const float* lng = (const float*)d_in[10];
  const float* lnb = (const float*)d_in[11];
  const float* Wpk = (const float*)d_in[12];
  const float* bpk = (const float*)d_in[13];
  const float* Wpq = (const float*)d_in[14];
  const float* bpq = (const float*)d_in[15];

  char* ws = (char*)d_ws;
  size_t off = 0;
  auto alloc = [&](size_t bytes){ size_t o = off; off += (bytes + 255) & ~(size_t)255; return o; };
  // ---- live-through-end region ----
  u16* Wo_t  = (u16*)(ws + alloc(1048576UL * 2));
  u16* Qd    = (u16*)(ws + alloc(4194304UL * 2));
  u16* Kd    = (u16*)(ws + alloc(4194304UL * 2));
  u16* Vtd   = (u16*)(ws + alloc(4194304UL * 2));
  u16* ECd   = (u16*)(ws + alloc(33554432UL * 2));
  u16* EPd   = (u16*)(ws + alloc(33554432UL * 2));
  u16* ctx   = (u16*)(ws + alloc(4194304UL * 2));
  u16* idxt  = (u16*)(ws + alloc(2048UL * 2));
  float* qkvb = (float*)(ws + alloc(3072UL * 4));
  float* posb = (float*)(ws + alloc(2048UL * 4));
  // ---- dead-after-EC/EP-GEMM region (EB aliases from here) ----
  size_t dead0 = off;
  u16* h_bf  = (u16*)(ws + alloc(4194304UL * 2));
  u16* Wt5   = (u16*)(ws + alloc(5UL * 1048576 * 2));
  u16* re_bf = (u16*)(ws + alloc(524288UL * 2));
  u16* posk  = (u16*)(ws + alloc(524288UL * 2));
  u16* posq  = (u16*)(ws + alloc(524288UL * 2));
  u16* EB    = (u16*)(ws + dead0);
  const bool full = (ws_size >= dead0 + 134217728UL);
  (void)posq; (void)Kd;

  k_prep<<<6145, 256, 0, stream>>>(hs, Wq, Wk, Wv, Wpk, Wpq, Wo, rel, lng, lnb,
                                   bq, bk, bv, bpk, bpq,
                                   h_bf, Wt5, Wo_t, re_bf, idxt, qkvb, posb);

  // fused QKV (2D-XCD-chunked, by<32) + pos GEMM (by in [32,36), bx<16); 64KB dyn LDS
  k_gemm<5><<<dim3(24, 36, 1), 256, 65536, stream>>>(h_bf, Wt5, qkvb, Qd, Vtd,
                                                     4096, 3072, 1024, 1024, 1024,
                                                     re_bf, posb, posk);
  // EC (z<64) / EP (z>=64), batched over bh; epilogue applies exp2; 32KB dyn LDS
  k_gemm<4><<<dim3(4, 8, 128), 256, 32768, stream>>>(Qd, posk, nullptr, ECd, nullptr,
                                                     1024, 512, 64, 64, 64,
                                                     nullptr, nullptr, nullptr);

  if (full){
    k_bias   <<<dim3(2048), 256, 0, stream>>>(ECd, EPd, idxt, EB, 0);
    k_attn_eb<<<dim3(1024), 256, 0, stream>>>(Qd, Kd, Vtd, EB, ctx, 0);
  } else {
    k_bias   <<<dim3(1024), 256, 0, stream>>>(ECd, EPd, idxt, EB, 0);
    k_attn_eb<<<dim3(512),  256, 0, stream>>>(Qd, Kd, Vtd, EB, ctx, 0);
    k_bias   <<<dim3(1024), 256, 0, stream>>>(ECd, EPd, idxt, EB, 32);
    k_attn_eb<<<dim3(512),  256, 0, stream>>>(Qd, Kd, Vtd, EB, ctx, 32);
  }

  // output projection (f32 out, XCD-swizzled, pipelined); 64KB dyn LDS
  k_gemm<0><<<dim3(8, 32, 1), 256, 65536, stream>>>(ctx, Wo_t, bo, d_out, nullptr,
                                                    4096, 1024, 1024, 1024, 1024,
                                                    nullptr, nullptr, nullptr);
}